// Round 1
// baseline (5041.705 us; speedup 1.0000x reference)
//
#include <hip/hip_runtime.h>
#include <hip/hip_bf16.h>

#define S_DIM 512
#define N_DIM 384
#define CM 64
#define CZ 128
#define HEADS 8
#define DH 32
#define HD 256

typedef __hip_bfloat16 bf16;

__device__ __forceinline__ float bf2f(bf16 x) { return __bfloat162float(x); }
__device__ __forceinline__ bf16 f2bf(float x) { return __float2bfloat16(x); }

// ---------------- LayerNorm of m0 -> mn (bf16) ------------------------------
// one wave per 64-elem row
__global__ __launch_bounds__(256) void k_ln_m(const float* __restrict__ m,
                                              const float* __restrict__ w,
                                              const float* __restrict__ b,
                                              bf16* __restrict__ mn) {
  int row = blockIdx.x * 4 + (threadIdx.x >> 6);
  int lane = threadIdx.x & 63;
  float x = m[(size_t)row * CM + lane];
  float s = x, sq = x * x;
#pragma unroll
  for (int off = 32; off; off >>= 1) {
    s += __shfl_xor(s, off);
    sq += __shfl_xor(sq, off);
  }
  float mu = s * (1.0f / CM);
  float var = sq * (1.0f / CM) - mu * mu;
  float rs = rsqrtf(var + 1e-5f);
  mn[(size_t)row * CM + lane] = f2bf((x - mu) * rs * w[lane] + b[lane]);
}

// ---------------- LN(z) + pair-bias logits ---------------------------------
// one wave per z row (128 elems, 2 per lane); logits stored [i][h][j]
__global__ __launch_bounds__(256) void k_zb(const float* __restrict__ z,
                                            const float* __restrict__ w,
                                            const float* __restrict__ b,
                                            const float* __restrict__ wz,
                                            float* __restrict__ logits) {
  int row = blockIdx.x * 4 + (threadIdx.x >> 6);  // row = i*384 + j
  int lane = threadIdx.x & 63;
  const float* x = z + (size_t)row * CZ;
  float v0 = x[lane], v1 = x[lane + 64];
  float s = v0 + v1, sq = v0 * v0 + v1 * v1;
#pragma unroll
  for (int off = 32; off; off >>= 1) {
    s += __shfl_xor(s, off);
    sq += __shfl_xor(sq, off);
  }
  float mu = s * (1.0f / CZ);
  float var = sq * (1.0f / CZ) - mu * mu;
  float rs = rsqrtf(var + 1e-5f);
  float zn0 = (v0 - mu) * rs * w[lane] + b[lane];
  float zn1 = (v1 - mu) * rs * w[lane + 64] + b[lane + 64];
  int i = row / N_DIM, j = row - i * N_DIM;
  for (int h = 0; h < HEADS; ++h) {
    float p = zn0 * wz[lane * HEADS + h] + zn1 * wz[(lane + 64) * HEADS + h];
#pragma unroll
    for (int off = 32; off; off >>= 1) p += __shfl_xor(p, off);
    if (lane == 0) logits[((size_t)i * HEADS + h) * N_DIM + j] = p;
  }
}

// ---------------- softmax over j (rows of 384), in place --------------------
__global__ __launch_bounds__(128) void k_softmax(float* __restrict__ wb) {
  float* p = wb + (size_t)blockIdx.x * N_DIM;
  int t = threadIdx.x;
  float a0 = p[t], a1 = p[t + 128], a2 = p[t + 256];
  float mx = fmaxf(a0, fmaxf(a1, a2));
  __shared__ float red[2], red2[2];
#pragma unroll
  for (int off = 32; off; off >>= 1) mx = fmaxf(mx, __shfl_xor(mx, off));
  if ((t & 63) == 0) red[t >> 6] = mx;
  __syncthreads();
  mx = fmaxf(red[0], red[1]);
  float e0 = __expf(a0 - mx), e1 = __expf(a1 - mx), e2 = __expf(a2 - mx);
  float s = e0 + e1 + e2;
#pragma unroll
  for (int off = 32; off; off >>= 1) s += __shfl_xor(s, off);
  if ((t & 63) == 0) red2[t >> 6] = s;
  __syncthreads();
  float inv = 1.0f / (red2[0] + red2[1]);
  p[t] = e0 * inv;
  p[t + 128] = e1 * inv;
  p[t + 256] = e2 * inv;
}

// ---------------- v = mn @ wm  (64-row tile x 256 cols) ---------------------
__global__ __launch_bounds__(256) void k_vgemm(const bf16* __restrict__ mn,
                                               const float* __restrict__ wm,
                                               bf16* __restrict__ v) {
  int blk = blockIdx.x;
  int s = blk / 6, j0 = (blk % 6) * 64;
  __shared__ bf16 al[64][72];    // [row][k]
  __shared__ bf16 bl[64][264];   // [k][c]
  int t = threadIdx.x;
  size_t rb = (size_t)s * N_DIM + j0;
  for (int idx = t; idx < 4096; idx += 256) {
    int r = idx >> 6, k = idx & 63;
    al[r][k] = mn[(rb + r) * CM + k];
  }
  for (int idx = t; idx < 16384; idx += 256)
    bl[idx >> 8][idx & 255] = f2bf(wm[idx]);
  __syncthreads();
  int tr = t >> 4, tc = t & 15;
  float acc[4][16];
#pragma unroll
  for (int r = 0; r < 4; ++r)
#pragma unroll
    for (int c = 0; c < 16; ++c) acc[r][c] = 0.0f;
  for (int k = 0; k < 64; ++k) {
    float a4[4];
#pragma unroll
    for (int r = 0; r < 4; ++r) a4[r] = bf2f(al[tr * 4 + r][k]);
#pragma unroll
    for (int c = 0; c < 16; ++c) {
      float bv = bf2f(bl[k][tc + 16 * c]);
#pragma unroll
      for (int r = 0; r < 4; ++r) acc[r][c] += a4[r] * bv;
    }
  }
#pragma unroll
  for (int r = 0; r < 4; ++r) {
    size_t base = (rb + tr * 4 + r) * HD;
#pragma unroll
    for (int c = 0; c < 16; ++c) v[base + tc + 16 * c] = f2bf(acc[r][c]);
  }
}

// ---------------- o_h = W_h @ V_h  (per-head, 64x64 tiles, K=384) -----------
// grid: (1536, 8): x = ib*256+nb, y = h
__global__ __launch_bounds__(256) void k_ogemm(const float* __restrict__ wsm,
                                               const bf16* __restrict__ v,
                                               bf16* __restrict__ o) {
  int h = blockIdx.y;
  int ib = blockIdx.x >> 8, nb = blockIdx.x & 255;
  int i0 = ib * 64, n0 = nb * 64;
  __shared__ bf16 wl[64][72];  // [i][j]
  __shared__ bf16 vl[64][72];  // [j][n]
  int t = threadIdx.x, tr = t >> 4, tc = t & 15;
  float acc[4][4];
#pragma unroll
  for (int r = 0; r < 4; ++r)
#pragma unroll
    for (int c = 0; c < 4; ++c) acc[r][c] = 0.0f;
  for (int j0 = 0; j0 < N_DIM; j0 += 64) {
    for (int idx = t; idx < 4096; idx += 256) {
      int a = idx >> 6, bcol = idx & 63;
      wl[a][bcol] = f2bf(wsm[(size_t)(i0 + a) * (HEADS * N_DIM) + h * N_DIM + j0 + bcol]);
      int n = n0 + bcol;
      vl[a][bcol] = v[((size_t)(n >> 5) * N_DIM + j0 + a) * HD + h * DH + (n & 31)];
    }
    __syncthreads();
    for (int k = 0; k < 64; ++k) {
      float a4[4], b4[4];
#pragma unroll
      for (int r = 0; r < 4; ++r) a4[r] = bf2f(wl[tr * 4 + r][k]);
#pragma unroll
      for (int c = 0; c < 4; ++c) b4[c] = bf2f(vl[k][tc * 4 + c]);
#pragma unroll
      for (int r = 0; r < 4; ++r)
#pragma unroll
        for (int c = 0; c < 4; ++c) acc[r][c] += a4[r] * b4[c];
    }
    __syncthreads();
  }
#pragma unroll
  for (int r = 0; r < 4; ++r)
#pragma unroll
    for (int c = 0; c < 4; ++c) {
      int n = n0 + tc * 4 + c;
      int i = i0 + tr * 4 + r;
      o[((size_t)(n >> 5) * N_DIM + i) * HD + h * DH + (n & 31)] = f2bf(acc[r][c]);
    }
}

// ---------------- pwa out: g=sigmoid(mn@wg); m1 = m0 + (o*g)@wo -------------
__global__ __launch_bounds__(256) void k_pwa_out(const bf16* __restrict__ mn,
                                                 const bf16* __restrict__ o,
                                                 const float* __restrict__ m0,
                                                 const float* __restrict__ wg,
                                                 const float* __restrict__ wo,
                                                 float* __restrict__ m1out) {
  int blk = blockIdx.x;
  int s = blk / 6, j0 = (blk % 6) * 64;
  __shared__ bf16 al[64][72];
  __shared__ bf16 wgl[64][264];
  __shared__ bf16 ogl[64][72];
  __shared__ bf16 wol[64][72];
  int t = threadIdx.x, tr = t >> 4, tc = t & 15;
  size_t rb = (size_t)s * N_DIM + j0;
  for (int idx = t; idx < 4096; idx += 256) {
    int r = idx >> 6, k = idx & 63;
    al[r][k] = mn[(rb + r) * CM + k];
  }
  for (int idx = t; idx < 16384; idx += 256)
    wgl[idx >> 8][idx & 255] = f2bf(wg[idx]);
  __syncthreads();
  float og[4][16];
#pragma unroll
  for (int r = 0; r < 4; ++r)
#pragma unroll
    for (int c = 0; c < 16; ++c) og[r][c] = 0.0f;
  for (int k = 0; k < 64; ++k) {
    float a4[4];
#pragma unroll
    for (int r = 0; r < 4; ++r) a4[r] = bf2f(al[tr * 4 + r][k]);
#pragma unroll
    for (int c = 0; c < 16; ++c) {
      float wv = bf2f(wgl[k][tc + 16 * c]);
#pragma unroll
      for (int r = 0; r < 4; ++r) og[r][c] += a4[r] * wv;
    }
  }
#pragma unroll
  for (int r = 0; r < 4; ++r)
#pragma unroll
    for (int c = 0; c < 16; ++c) {
      float g = 1.0f / (1.0f + __expf(-og[r][c]));
    float ov = bf2f(o[(rb + tr * 4 + r) * HD + tc + 16 * c]);
      og[r][c] = g * ov;
    }
  float outa[4][4];
#pragma unroll
  for (int r = 0; r < 4; ++r)
#pragma unroll
    for (int c = 0; c < 4; ++c) outa[r][c] = 0.0f;
  for (int kc = 0; kc < 4; ++kc) {
    __syncthreads();
#pragma unroll
    for (int r = 0; r < 4; ++r)
#pragma unroll
      for (int cc = 0; cc < 4; ++cc)
        ogl[tr * 4 + r][tc + 16 * cc] = f2bf(og[r][kc * 4 + cc]);
    for (int idx = t; idx < 4096; idx += 256) {
      int kk = idx >> 6, n = idx & 63;
      wol[kk][n] = f2bf(wo[(size_t)(kc * 64 + kk) * CM + n]);
    }
    __syncthreads();
    for (int kk = 0; kk < 64; ++kk) {
      float a4[4], b4[4];
#pragma unroll
      for (int r = 0; r < 4; ++r) a4[r] = bf2f(ogl[tr * 4 + r][kk]);
#pragma unroll
      for (int c = 0; c < 4; ++c) b4[c] = bf2f(wol[kk][tc * 4 + c]);
#pragma unroll
      for (int r = 0; r < 4; ++r)
#pragma unroll
        for (int c = 0; c < 4; ++c) outa[r][c] += a4[r] * b4[c];
    }
  }
#pragma unroll
  for (int r = 0; r < 4; ++r)
#pragma unroll
    for (int c = 0; c < 4; ++c) {
      size_t a = (rb + tr * 4 + r) * CM + tc * 4 + c;
      m1out[a] = m0[a] + outa[r][c];
    }
}

// ---------------- transition: m2 = m1 + (silu(tn@w1)*(tn@w2))@w3 ------------
__global__ __launch_bounds__(256) void k_transition(const float* __restrict__ nw,
                                                    const float* __restrict__ nb,
                                                    const float* __restrict__ w1,
                                                    const float* __restrict__ w2,
                                                    const float* __restrict__ w3,
                                                    float* __restrict__ mio) {
  size_t rb = (size_t)blockIdx.x * 64;
  __shared__ bf16 al[64][72];
  __shared__ bf16 wl[64][264];
  __shared__ bf16 hgl[64][72];
  __shared__ bf16 w3l[64][72];
  int t = threadIdx.x, tr = t >> 4, tc = t & 15;
  int wv = t >> 6, ln = t & 63;
  for (int rr = wv; rr < 64; rr += 4) {
    float x = mio[(rb + rr) * CM + ln];
    float s = x, sq = x * x;
#pragma unroll
    for (int off = 32; off; off >>= 1) {
      s += __shfl_xor(s, off);
      sq += __shfl_xor(sq, off);
    }
    float mu = s * (1.0f / CM);
    float var = sq * (1.0f / CM) - mu * mu;
    float rs = rsqrtf(var + 1e-5f);
    al[rr][ln] = f2bf((x - mu) * rs * nw[ln] + nb[ln]);
  }
  for (int idx = t; idx < 16384; idx += 256)
    wl[idx >> 8][idx & 255] = f2bf(w1[idx]);
  __syncthreads();
  float acc1[4][16], acc2[4][16];
#pragma unroll
  for (int r = 0; r < 4; ++r)
#pragma unroll
    for (int c = 0; c < 16; ++c) acc1[r][c] = 0.0f;
  for (int k = 0; k < 64; ++k) {
    float a4[4];
#pragma unroll
    for (int r = 0; r < 4; ++r) a4[r] = bf2f(al[tr * 4 + r][k]);
#pragma unroll
    for (int c = 0; c < 16; ++c) {
      float wvv = bf2f(wl[k][tc + 16 * c]);
#pragma unroll
      for (int r = 0; r < 4; ++r) acc1[r][c] += a4[r] * wvv;
    }
  }
  __syncthreads();
  for (int idx = t; idx < 16384; idx += 256)
    wl[idx >> 8][idx & 255] = f2bf(w2[idx]);
  __syncthreads();
#pragma unroll
  for (int r = 0; r < 4; ++r)
#pragma unroll
    for (int c = 0; c < 16; ++c) acc2[r][c] = 0.0f;
  for (int k = 0; k < 64; ++k) {
    float a4[4];
#pragma unroll
    for (int r = 0; r < 4; ++r) a4[r] = bf2f(al[tr * 4 + r][k]);
#pragma unroll
    for (int c = 0; c < 16; ++c) {
      float wvv = bf2f(wl[k][tc + 16 * c]);
#pragma unroll
      for (int r = 0; r < 4; ++r) acc2[r][c] += a4[r] * wvv;
    }
  }
#pragma unroll
  for (int r = 0; r < 4; ++r)
#pragma unroll
    for (int c = 0; c < 16; ++c) {
      float x = acc1[r][c];
      acc1[r][c] = (x / (1.0f + __expf(-x))) * acc2[r][c];
    }
  float outa[4][4];
#pragma unroll
  for (int r = 0; r < 4; ++r)
#pragma unroll
    for (int c = 0; c < 4; ++c) outa[r][c] = 0.0f;
  for (int kc = 0; kc < 4; ++kc) {
    __syncthreads();
#pragma unroll
    for (int r = 0; r < 4; ++r)
#pragma unroll
      for (int cc = 0; cc < 4; ++cc)
        hgl[tr * 4 + r][tc + 16 * cc] = f2bf(acc1[r][kc * 4 + cc]);
    for (int idx = t; idx < 4096; idx += 256) {
      int kk = idx >> 6, n = idx & 63;
      w3l[kk][n] = f2bf(w3[(size_t)(kc * 64 + kk) * CM + n]);
    }
    __syncthreads();
    for (int kk = 0; kk < 64; ++kk) {
      float a4[4], b4[4];
#pragma unroll
      for (int r = 0; r < 4; ++r) a4[r] = bf2f(hgl[tr * 4 + r][kk]);
#pragma unroll
      for (int c = 0; c < 4; ++c) b4[c] = bf2f(w3l[kk][tc * 4 + c]);
#pragma unroll
      for (int r = 0; r < 4; ++r)
#pragma unroll
        for (int c = 0; c < 4; ++c) outa[r][c] += a4[r] * b4[c];
    }
  }
#pragma unroll
  for (int r = 0; r < 4; ++r)
#pragma unroll
    for (int c = 0; c < 4; ++c) {
      size_t a = (rb + tr * 4 + r) * CM + tc * 4 + c;
      mio[a] = mio[a] + outa[r][c];
    }
}

// ---------------- opm a/b: on = LN(m2); a = on@wa, b = on@wb (K-major out) --
__global__ __launch_bounds__(256) void k_opm_ab(const float* __restrict__ m2,
                                                const float* __restrict__ nw,
                                                const float* __restrict__ nb,
                                                const float* __restrict__ wa,
                                                const float* __restrict__ wb,
                                                float* __restrict__ at,
                                                float* __restrict__ bt) {
  int row = blockIdx.x * 4 + (threadIdx.x >> 6);  // s*384 + i
  int lane = threadIdx.x & 63;
  int wv = threadIdx.x >> 6;
  __shared__ float on[4][64];
  float x = m2[(size_t)row * CM + lane];
  float s = x, sq = x * x;
#pragma unroll
  for (int off = 32; off; off >>= 1) {
    s += __shfl_xor(s, off);
    sq += __shfl_xor(sq, off);
  }
  float mu = s * (1.0f / CM);
  float var = sq * (1.0f / CM) - mu * mu;
  float rs = rsqrtf(var + 1e-5f);
  on[wv][lane] = (x - mu) * rs * nw[lane] + nb[lane];
  __syncthreads();
  const float* wsel = (lane < 32) ? wa : wb;
  int c = lane & 31;
  float acc = 0.0f;
  for (int k = 0; k < 64; ++k) acc += on[wv][k] * wsel[k * 32 + c];
  int si = row / N_DIM, i = row - si * N_DIM;
  float* outp = (lane < 32) ? at : bt;
  outp[(size_t)si * (N_DIM * 32) + i * 32 + c] = acc;
}

// ---------------- OPM: op-tile GEMM (128x128, K=512) + fused projection -----
// grid (96,96). C[(i,c),(j,d)] = sum_s at[s][ic] * bt[s][jd]; then per (i,j)
// pair: z1 = z0 + op_flat @ wo + bo, with wo streamed once per block.
__global__ __launch_bounds__(256) void k_opm(const float* __restrict__ at,
                                             const float* __restrict__ bt,
                                             const float* __restrict__ wo,
                                             const float* __restrict__ bo,
                                             const float* __restrict__ z0,
                                             float* __restrict__ z1) {
  int bm = blockIdx.x, bn = blockIdx.y;
  __shared__ float al[16][132];
  __shared__ float bl[16][132];
  __shared__ float opc[16][132];
  __shared__ bf16 wol[128][136];
  int t = threadIdx.x, tm = t >> 4, tn = t & 15;
  float acc[8][8];
#pragma unroll
  for (int r = 0; r < 8; ++r)
#pragma unroll
    for (int c = 0; c < 8; ++c) acc[r][c] = 0.0f;
  for (int k0 = 0; k0 < 512; k0 += 16) {
    for (int idx = t; idx < 2048; idx += 256) {
      int k = idx >> 7, mcol = idx & 127;
      al[k][mcol] = at[(size_t)(k0 + k) * 12288 + bm * 128 + mcol];
      bl[k][mcol] = bt[(size_t)(k0 + k) * 12288 + bn * 128 + mcol];
    }
    __syncthreads();
    for (int k = 0; k < 16; ++k) {
      float av[8], bv[8];
#pragma unroll
      for (int r = 0; r < 8; ++r) av[r] = al[k][tm * 8 + r];
#pragma unroll
      for (int c = 0; c < 8; ++c) bv[c] = bl[k][tn * 8 + c];
#pragma unroll
      for (int r = 0; r < 8; ++r)
#pragma unroll
        for (int c = 0; c < 8; ++c) acc[r][c] += av[r] * bv[c];
    }
    __syncthreads();
  }
  // fused projection: 8 chunks of 128 cd each (4 c-values x 32 d)
  float zacc[8];
#pragma unroll
  for (int p = 0; p < 8; ++p) zacc[p] = 0.0f;
  int kcol = t & 127, pg = t >> 7;
  for (int q = 0; q < 8; ++q) {
    __syncthreads();
    if ((tm & 3) == (q >> 1)) {
      int ii = tm >> 2;
      int jj = tn >> 2;
      int p = ii * 4 + jj;
#pragma unroll
      for (int cc = 0; cc < 4; ++cc) {
        int r = (q & 1) * 4 + cc;
#pragma unroll
        for (int dd = 0; dd < 8; ++dd) {
          int d = (tn & 3) * 8 + dd;
          opc[p][cc * 32 + d] = acc[r][dd] * (1.0f / 512.0f);
        }
      }
    }
    for (int idx = t; idx < 16384; idx += 256)
      wol[idx >> 7][idx & 127] = f2bf(wo[(size_t)q * 16384 + idx]);
    __syncthreads();
    for (int cdl = 0; cdl < 128; ++cdl) {
      float wv = bf2f(wol[cdl][kcol]);
#pragma unroll
      for (int p = 0; p < 8; ++p) zacc[p] += opc[pg * 8 + p][cdl] * wv;
    }
  }
  float bov = bo[kcol];
#pragma unroll
  for (int p = 0; p < 8; ++p) {
    int pair = pg * 8 + p;
    int gi = bm * 4 + (pair >> 2), gj = bn * 4 + (pair & 3);
    size_t addr = ((size_t)gi * N_DIM + gj) * CZ + kcol;
    z1[addr] = z0[addr] + zacc[p] + bov;
  }
}

// ---------------------------------------------------------------------------
extern "C" void kernel_launch(void* const* d_in, const int* in_sizes, int n_in,
                              void* d_out, int out_size, void* d_ws, size_t ws_size,
                              hipStream_t stream) {
  const float* m0 = (const float*)d_in[0];
  const float* z0 = (const float*)d_in[1];
  const float* pwa_nm_w = (const float*)d_in[2];
  const float* pwa_nm_b = (const float*)d_in[3];
  const float* pwa_nz_w = (const float*)d_in[4];
  const float* pwa_nz_b = (const float*)d_in[5];
  const float* pwa_wm = (const float*)d_in[6];
  const float* pwa_wg = (const float*)d_in[7];
  const float* pwa_wz = (const float*)d_in[8];
  const float* pwa_wo = (const float*)d_in[9];
  const float* tr_nw = (const float*)d_in[10];
  const float* tr_nb = (const float*)d_in[11];
  const float* tr_w1 = (const float*)d_in[12];
  const float* tr_w2 = (const float*)d_in[13];
  const float* tr_w3 = (const float*)d_in[14];
  const float* opm_nw = (const float*)d_in[15];
  const float* opm_nb = (const float*)d_in[16];
  const float* opm_wa = (const float*)d_in[17];
  const float* opm_wb = (const float*)d_in[18];
  const float* opm_wo = (const float*)d_in[19];
  const float* opm_bo = (const float*)d_in[20];

  // workspace arena (peak ~220.5 MiB)
  char* ws = (char*)d_ws;
  bf16* mn = (bf16*)(ws);                        // 25,165,824 B
  float* wbuf = (float*)(ws + 25165824);         //  4,718,592 B
  bf16* v = (bf16*)(ws + 29884416);              // 100,663,296 B
  bf16* o = (bf16*)(ws + 130547712);             // 100,663,296 B
  float* at = (float*)(ws + 29884416);           // reuses dead v region
  float* bt = (float*)(ws + 55050240);

  float* m_out = (float*)d_out;                  // m2 region (m1 staged here)
  float* z1 = m_out + (size_t)S_DIM * N_DIM * CM;

  k_ln_m<<<49152, 256, 0, stream>>>(m0, pwa_nm_w, pwa_nm_b, mn);
  k_zb<<<36864, 256, 0, stream>>>(z0, pwa_nz_w, pwa_nz_b, pwa_wz, wbuf);
  k_softmax<<<3072, 128, 0, stream>>>(wbuf);
  k_vgemm<<<3072, 256, 0, stream>>>(mn, pwa_wm, v);
  k_ogemm<<<dim3(1536, 8), 256, 0, stream>>>(wbuf, v, o);
  k_pwa_out<<<3072, 256, 0, stream>>>(mn, o, m0, pwa_wg, pwa_wo, m_out);
  k_transition<<<3072, 256, 0, stream>>>(tr_nw, tr_nb, tr_w1, tr_w2, tr_w3, m_out);
  k_opm_ab<<<49152, 256, 0, stream>>>(m_out, opm_nw, opm_nb, opm_wa, opm_wb, at, bt);
  k_opm<<<dim3(96, 96), 256, 0, stream>>>(at, bt, opm_wo, opm_bo, z0, z1);
}

// Round 2
// 2750.540 us; speedup vs baseline: 1.8330x; 1.8330x over previous
//
#include <hip/hip_runtime.h>
#include <hip/hip_bf16.h>

#define S_DIM 512
#define N_DIM 384
#define CM 64
#define CZ 128
#define HEADS 8
#define DH 32
#define HD 256

typedef __hip_bfloat16 bf16;
typedef __attribute__((ext_vector_type(8))) short bf16x8;
typedef __attribute__((ext_vector_type(4))) float f32x4;

__device__ __forceinline__ float bf2f(bf16 x) { return __bfloat162float(x); }
__device__ __forceinline__ bf16 f2bf(float x) { return __float2bfloat16(x); }
__device__ __forceinline__ short f2bs(float x) {
  bf16 h = __float2bfloat16(x);
  return *reinterpret_cast<short*>(&h);
}

// ---------------- LayerNorm of m0 -> mn (bf16) ------------------------------
__global__ __launch_bounds__(256) void k_ln_m(const float* __restrict__ m,
                                              const float* __restrict__ w,
                                              const float* __restrict__ b,
                                              bf16* __restrict__ mn) {
  int row = blockIdx.x * 4 + (threadIdx.x >> 6);
  int lane = threadIdx.x & 63;
  float x = m[(size_t)row * CM + lane];
  float s = x, sq = x * x;
#pragma unroll
  for (int off = 32; off; off >>= 1) {
    s += __shfl_xor(s, off);
    sq += __shfl_xor(sq, off);
  }
  float mu = s * (1.0f / CM);
  float var = sq * (1.0f / CM) - mu * mu;
  float rs = rsqrtf(var + 1e-5f);
  mn[(size_t)row * CM + lane] = f2bf((x - mu) * rs * w[lane] + b[lane]);
}

// ---------------- LN(z) + pair-bias logits ---------------------------------
__global__ __launch_bounds__(256) void k_zb(const float* __restrict__ z,
                                            const float* __restrict__ w,
                                            const float* __restrict__ b,
                                            const float* __restrict__ wz,
                                            float* __restrict__ logits) {
  int row = blockIdx.x * 4 + (threadIdx.x >> 6);  // row = i*384 + j
  int lane = threadIdx.x & 63;
  const float* x = z + (size_t)row * CZ;
  float v0 = x[lane], v1 = x[lane + 64];
  float s = v0 + v1, sq = v0 * v0 + v1 * v1;
#pragma unroll
  for (int off = 32; off; off >>= 1) {
    s += __shfl_xor(s, off);
    sq += __shfl_xor(sq, off);
  }
  float mu = s * (1.0f / CZ);
  float var = sq * (1.0f / CZ) - mu * mu;
  float rs = rsqrtf(var + 1e-5f);
  float zn0 = (v0 - mu) * rs * w[lane] + b[lane];
  float zn1 = (v1 - mu) * rs * w[lane + 64] + b[lane + 64];
  int i = row / N_DIM, j = row - i * N_DIM;
  for (int h = 0; h < HEADS; ++h) {
    float p = zn0 * wz[lane * HEADS + h] + zn1 * wz[(lane + 64) * HEADS + h];
#pragma unroll
    for (int off = 32; off; off >>= 1) p += __shfl_xor(p, off);
    if (lane == 0) logits[((size_t)i * HEADS + h) * N_DIM + j] = p;
  }
}

// ---------------- softmax over j (rows of 384), in place --------------------
__global__ __launch_bounds__(128) void k_softmax(float* __restrict__ wb) {
  float* p = wb + (size_t)blockIdx.x * N_DIM;
  int t = threadIdx.x;
  float a0 = p[t], a1 = p[t + 128], a2 = p[t + 256];
  float mx = fmaxf(a0, fmaxf(a1, a2));
  __shared__ float red[2], red2[2];
#pragma unroll
  for (int off = 32; off; off >>= 1) mx = fmaxf(mx, __shfl_xor(mx, off));
  if ((t & 63) == 0) red[t >> 6] = mx;
  __syncthreads();
  mx = fmaxf(red[0], red[1]);
  float e0 = __expf(a0 - mx), e1 = __expf(a1 - mx), e2 = __expf(a2 - mx);
  float s = e0 + e1 + e2;
#pragma unroll
  for (int off = 32; off; off >>= 1) s += __shfl_xor(s, off);
  if ((t & 63) == 0) red2[t >> 6] = s;
  __syncthreads();
  float inv = 1.0f / (red2[0] + red2[1]);
  p[t] = e0 * inv;
  p[t + 128] = e1 * inv;
  p[t + 256] = e2 * inv;
}

// ---------------- v = mn @ wm  (64-row tile x 256 cols) ---------------------
__global__ __launch_bounds__(256) void k_vgemm(const bf16* __restrict__ mn,
                                               const float* __restrict__ wm,
                                               bf16* __restrict__ v) {
  int blk = blockIdx.x;
  int s = blk / 6, j0 = (blk % 6) * 64;
  __shared__ bf16 al[64][72];
  __shared__ bf16 bl[64][264];
  int t = threadIdx.x;
  size_t rb = (size_t)s * N_DIM + j0;
  for (int idx = t; idx < 4096; idx += 256) {
    int r = idx >> 6, k = idx & 63;
    al[r][k] = mn[(rb + r) * CM + k];
  }
  for (int idx = t; idx < 16384; idx += 256)
    bl[idx >> 8][idx & 255] = f2bf(wm[idx]);
  __syncthreads();
  int tr = t >> 4, tc = t & 15;
  float acc[4][16];
#pragma unroll
  for (int r = 0; r < 4; ++r)
#pragma unroll
    for (int c = 0; c < 16; ++c) acc[r][c] = 0.0f;
  for (int k = 0; k < 64; ++k) {
    float a4[4];
#pragma unroll
    for (int r = 0; r < 4; ++r) a4[r] = bf2f(al[tr * 4 + r][k]);
#pragma unroll
    for (int c = 0; c < 16; ++c) {
      float bv = bf2f(bl[k][tc + 16 * c]);
#pragma unroll
      for (int r = 0; r < 4; ++r) acc[r][c] += a4[r] * bv;
    }
  }
#pragma unroll
  for (int r = 0; r < 4; ++r) {
    size_t base = (rb + tr * 4 + r) * HD;
#pragma unroll
    for (int c = 0; c < 16; ++c) v[base + tc + 16 * c] = f2bf(acc[r][c]);
  }
}

// ---------------- o_h = W_h @ V_h  (per-head, 64x64 tiles, K=384) -----------
__global__ __launch_bounds__(256) void k_ogemm(const float* __restrict__ wsm,
                                               const bf16* __restrict__ v,
                                               bf16* __restrict__ o) {
  int h = blockIdx.y;
  int ib = blockIdx.x >> 8, nb = blockIdx.x & 255;
  int i0 = ib * 64, n0 = nb * 64;
  __shared__ bf16 wl[64][72];
  __shared__ bf16 vl[64][72];
  int t = threadIdx.x, tr = t >> 4, tc = t & 15;
  float acc[4][4];
#pragma unroll
  for (int r = 0; r < 4; ++r)
#pragma unroll
    for (int c = 0; c < 4; ++c) acc[r][c] = 0.0f;
  for (int j0 = 0; j0 < N_DIM; j0 += 64) {
    for (int idx = t; idx < 4096; idx += 256) {
      int a = idx >> 6, bcol = idx & 63;
      wl[a][bcol] = f2bf(wsm[(size_t)(i0 + a) * (HEADS * N_DIM) + h * N_DIM + j0 + bcol]);
      int n = n0 + bcol;
      vl[a][bcol] = v[((size_t)(n >> 5) * N_DIM + j0 + a) * HD + h * DH + (n & 31)];
    }
    __syncthreads();
    for (int k = 0; k < 64; ++k) {
      float a4[4], b4[4];
#pragma unroll
      for (int r = 0; r < 4; ++r) a4[r] = bf2f(wl[tr * 4 + r][k]);
#pragma unroll
      for (int c = 0; c < 4; ++c) b4[c] = bf2f(vl[k][tc * 4 + c]);
#pragma unroll
      for (int r = 0; r < 4; ++r)
#pragma unroll
        for (int c = 0; c < 4; ++c) acc[r][c] += a4[r] * b4[c];
    }
    __syncthreads();
  }
#pragma unroll
  for (int r = 0; r < 4; ++r)
#pragma unroll
    for (int c = 0; c < 4; ++c) {
      int n = n0 + tc * 4 + c;
      int i = i0 + tr * 4 + r;
      o[((size_t)(n >> 5) * N_DIM + i) * HD + h * DH + (n & 31)] = f2bf(acc[r][c]);
    }
}

// ---------------- pwa out: g=sigmoid(mn@wg); m1 = m0 + (o*g)@wo -------------
__global__ __launch_bounds__(256) void k_pwa_out(const bf16* __restrict__ mn,
                                                 const bf16* __restrict__ o,
                                                 const float* __restrict__ m0,
                                                 const float* __restrict__ wg,
                                                 const float* __restrict__ wo,
                                                 float* __restrict__ m1out) {
  int blk = blockIdx.x;
  int s = blk / 6, j0 = (blk % 6) * 64;
  __shared__ bf16 al[64][72];
  __shared__ bf16 wgl[64][264];
  __shared__ bf16 ogl[64][72];
  __shared__ bf16 wol[64][72];
  int t = threadIdx.x, tr = t >> 4, tc = t & 15;
  size_t rb = (size_t)s * N_DIM + j0;
  for (int idx = t; idx < 4096; idx += 256) {
    int r = idx >> 6, k = idx & 63;
    al[r][k] = mn[(rb + r) * CM + k];
  }
  for (int idx = t; idx < 16384; idx += 256)
    wgl[idx >> 8][idx & 255] = f2bf(wg[idx]);
  __syncthreads();
  float og[4][16];
#pragma unroll
  for (int r = 0; r < 4; ++r)
#pragma unroll
    for (int c = 0; c < 16; ++c) og[r][c] = 0.0f;
  for (int k = 0; k < 64; ++k) {
    float a4[4];
#pragma unroll
    for (int r = 0; r < 4; ++r) a4[r] = bf2f(al[tr * 4 + r][k]);
#pragma unroll
    for (int c = 0; c < 16; ++c) {
      float wv = bf2f(wgl[k][tc + 16 * c]);
#pragma unroll
      for (int r = 0; r < 4; ++r) og[r][c] += a4[r] * wv;
    }
  }
#pragma unroll
  for (int r = 0; r < 4; ++r)
#pragma unroll
    for (int c = 0; c < 16; ++c) {
      float g = 1.0f / (1.0f + __expf(-og[r][c]));
      float ov = bf2f(o[(rb + tr * 4 + r) * HD + tc + 16 * c]);
      og[r][c] = g * ov;
    }
  float outa[4][4];
#pragma unroll
  for (int r = 0; r < 4; ++r)
#pragma unroll
    for (int c = 0; c < 4; ++c) outa[r][c] = 0.0f;
  for (int kc = 0; kc < 4; ++kc) {
    __syncthreads();
#pragma unroll
    for (int r = 0; r < 4; ++r)
#pragma unroll
      for (int cc = 0; cc < 4; ++cc)
        ogl[tr * 4 + r][tc + 16 * cc] = f2bf(og[r][kc * 4 + cc]);
    for (int idx = t; idx < 4096; idx += 256) {
      int kk = idx >> 6, n = idx & 63;
      wol[kk][n] = f2bf(wo[(size_t)(kc * 64 + kk) * CM + n]);
    }
    __syncthreads();
    for (int kk = 0; kk < 64; ++kk) {
      float a4[4], b4[4];
#pragma unroll
      for (int r = 0; r < 4; ++r) a4[r] = bf2f(ogl[tr * 4 + r][kk]);
#pragma unroll
      for (int c = 0; c < 4; ++c) b4[c] = bf2f(wol[kk][tc * 4 + c]);
#pragma unroll
      for (int r = 0; r < 4; ++r)
#pragma unroll
        for (int c = 0; c < 4; ++c) outa[r][c] += a4[r] * b4[c];
    }
  }
#pragma unroll
  for (int r = 0; r < 4; ++r)
#pragma unroll
    for (int c = 0; c < 4; ++c) {
      size_t a = (rb + tr * 4 + r) * CM + tc * 4 + c;
      m1out[a] = m0[a] + outa[r][c];
    }
}

// ---------------- transition: m2 = m1 + (silu(tn@w1)*(tn@w2))@w3 ------------
__global__ __launch_bounds__(256) void k_transition(const float* __restrict__ nw,
                                                    const float* __restrict__ nb,
                                                    const float* __restrict__ w1,
                                                    const float* __restrict__ w2,
                                                    const float* __restrict__ w3,
                                                    float* __restrict__ mio) {
  size_t rb = (size_t)blockIdx.x * 64;
  __shared__ bf16 al[64][72];
  __shared__ bf16 wl[64][264];
  __shared__ bf16 hgl[64][72];
  __shared__ bf16 w3l[64][72];
  int t = threadIdx.x, tr = t >> 4, tc = t & 15;
  int wv = t >> 6, ln = t & 63;
  for (int rr = wv; rr < 64; rr += 4) {
    float x = mio[(rb + rr) * CM + ln];
    float s = x, sq = x * x;
#pragma unroll
    for (int off = 32; off; off >>= 1) {
      s += __shfl_xor(s, off);
      sq += __shfl_xor(sq, off);
    }
    float mu = s * (1.0f / CM);
    float var = sq * (1.0f / CM) - mu * mu;
    float rs = rsqrtf(var + 1e-5f);
    al[rr][ln] = f2bf((x - mu) * rs * nw[ln] + nb[ln]);
  }
  for (int idx = t; idx < 16384; idx += 256)
    wl[idx >> 8][idx & 255] = f2bf(w1[idx]);
  __syncthreads();
  float acc1[4][16], acc2[4][16];
#pragma unroll
  for (int r = 0; r < 4; ++r)
#pragma unroll
    for (int c = 0; c < 16; ++c) acc1[r][c] = 0.0f;
  for (int k = 0; k < 64; ++k) {
    float a4[4];
#pragma unroll
    for (int r = 0; r < 4; ++r) a4[r] = bf2f(al[tr * 4 + r][k]);
#pragma unroll
    for (int c = 0; c < 16; ++c) {
      float wvv = bf2f(wl[k][tc + 16 * c]);
#pragma unroll
      for (int r = 0; r < 4; ++r) acc1[r][c] += a4[r] * wvv;
    }
  }
  __syncthreads();
  for (int idx = t; idx < 16384; idx += 256)
    wl[idx >> 8][idx & 255] = f2bf(w2[idx]);
  __syncthreads();
#pragma unroll
  for (int r = 0; r < 4; ++r)
#pragma unroll
    for (int c = 0; c < 16; ++c) acc2[r][c] = 0.0f;
  for (int k = 0; k < 64; ++k) {
    float a4[4];
#pragma unroll
    for (int r = 0; r < 4; ++r) a4[r] = bf2f(al[tr * 4 + r][k]);
#pragma unroll
    for (int c = 0; c < 16; ++c) {
      float wvv = bf2f(wl[k][tc + 16 * c]);
#pragma unroll
      for (int r = 0; r < 4; ++r) acc2[r][c] += a4[r] * wvv;
    }
  }
#pragma unroll
  for (int r = 0; r < 4; ++r)
#pragma unroll
    for (int c = 0; c < 16; ++c) {
      float x = acc1[r][c];
      acc1[r][c] = (x / (1.0f + __expf(-x))) * acc2[r][c];
    }
  float outa[4][4];
#pragma unroll
  for (int r = 0; r < 4; ++r)
#pragma unroll
    for (int c = 0; c < 4; ++c) outa[r][c] = 0.0f;
  for (int kc = 0; kc < 4; ++kc) {
    __syncthreads();
#pragma unroll
    for (int r = 0; r < 4; ++r)
#pragma unroll
      for (int cc = 0; cc < 4; ++cc)
        hgl[tr * 4 + r][tc + 16 * cc] = f2bf(acc1[r][kc * 4 + cc]);
    for (int idx = t; idx < 4096; idx += 256) {
      int kk = idx >> 6, n = idx & 63;
      w3l[kk][n] = f2bf(w3[(size_t)(kc * 64 + kk) * CM + n]);
    }
    __syncthreads();
    for (int kk = 0; kk < 64; ++kk) {
      float a4[4], b4[4];
#pragma unroll
      for (int r = 0; r < 4; ++r) a4[r] = bf2f(hgl[tr * 4 + r][kk]);
#pragma unroll
      for (int c = 0; c < 4; ++c) b4[c] = bf2f(w3l[kk][tc * 4 + c]);
#pragma unroll
      for (int r = 0; r < 4; ++r)
#pragma unroll
        for (int c = 0; c < 4; ++c) outa[r][c] += a4[r] * b4[c];
    }
  }
#pragma unroll
  for (int r = 0; r < 4; ++r)
#pragma unroll
    for (int c = 0; c < 4; ++c) {
      size_t a = (rb + tr * 4 + r) * CM + tc * 4 + c;
      mio[a] = mio[a] + outa[r][c];
    }
}

// ---------------- opm a/b: LN(m2)@wa/wb -> bf16, [m][k] layout (k=s) --------
// block: 64 s-values x one i. outputs at_t[(i*32+c)*512 + s]
__global__ __launch_bounds__(256) void k_opm_ab(const float* __restrict__ m2,
                                                const float* __restrict__ nw,
                                                const float* __restrict__ nb,
                                                const float* __restrict__ wa,
                                                const float* __restrict__ wb,
                                                short* __restrict__ at_t,
                                                short* __restrict__ bt_t) {
  int bix = blockIdx.x;
  int sg = bix / N_DIM;
  int i = bix - sg * N_DIM;
  __shared__ float on[64][65];
  __shared__ float wl[2][64][36];
  __shared__ float tl[2][32][65];
  int t = threadIdx.x, w = t >> 6, lane = t & 63;
  float gw = nw[lane], gb = nb[lane];
  for (int rr = 0; rr < 16; ++rr) {
    int sl = w * 16 + rr;
    float x = m2[((size_t)(sg * 64 + sl) * N_DIM + i) * CM + lane];
    float s = x, sq = x * x;
#pragma unroll
    for (int off = 32; off; off >>= 1) {
      s += __shfl_xor(s, off);
      sq += __shfl_xor(sq, off);
    }
    float mu = s * (1.0f / CM);
    float var = sq * (1.0f / CM) - mu * mu;
    float rs = rsqrtf(var + 1e-5f);
    on[sl][lane] = (x - mu) * rs * gw + gb;
  }
  for (int idx = t; idx < 2048; idx += 256) {
    int k = idx >> 5, c = idx & 31;
    wl[0][k][c] = wa[idx];
    wl[1][k][c] = wb[idx];
  }
  __syncthreads();
  int s = t >> 2, c0 = (t & 3) * 8;
  float accA[8], accB[8];
#pragma unroll
  for (int j = 0; j < 8; ++j) { accA[j] = 0.0f; accB[j] = 0.0f; }
  for (int k = 0; k < 64; ++k) {
    float ov = on[s][k];
#pragma unroll
    for (int j = 0; j < 8; ++j) {
      accA[j] += ov * wl[0][k][c0 + j];
      accB[j] += ov * wl[1][k][c0 + j];
    }
  }
#pragma unroll
  for (int j = 0; j < 8; ++j) {
    tl[0][c0 + j][s] = accA[j];
    tl[1][c0 + j][s] = accB[j];
  }
  __syncthreads();
  size_t obase = (size_t)i * 32 * 512 + (size_t)sg * 64;
  for (int idx = t; idx < 2048; idx += 256) {
    int c = idx >> 6, s2 = idx & 63;
    at_t[obase + (size_t)c * 512 + s2] = f2bs(tl[0][c][s2]);
    bt_t[obase + (size_t)c * 512 + s2] = f2bs(tl[1][c][s2]);
  }
}

// ---------------- wo_t[e][cd] = bf16(wo[cd][e]) -----------------------------
__global__ __launch_bounds__(256) void k_wot(const float* __restrict__ wo,
                                             short* __restrict__ wo_t) {
  int k0 = blockIdx.x * 32;
  __shared__ float tile[32][129];
  int t = threadIdx.x;
  for (int idx = t; idx < 4096; idx += 256) {
    int k = idx >> 7, n = idx & 127;
    tile[k][n] = wo[(size_t)(k0 + k) * CZ + n];
  }
  __syncthreads();
  int n = t >> 1, kk0 = (t & 1) * 16;
  for (int j = 0; j < 16; ++j)
    wo_t[(size_t)n * 1024 + k0 + kk0 + j] = f2bs(tile[kk0 + j][n]);
}

// ---------------- OPM via MFMA: op tile 128x128 (K=512) + fused proj --------
// at_t/bt_t: bf16 [m][k], m = i*32+c (12288), k = s (512)
// wo_t: bf16 [e][cd] (128 x 1024)
__global__ __launch_bounds__(256) void k_opm(const short* __restrict__ at_t,
                                             const short* __restrict__ bt_t,
                                             const short* __restrict__ wo_t,
                                             const float* __restrict__ bo,
                                             const float* __restrict__ z0,
                                             float* __restrict__ z1) {
  int bm = blockIdx.x, bn = blockIdx.y;
  // A tile: lds[0 .. 128*72), B tile: lds[9216 .. 9216+9216)
  // P (proj A): reuses lds[0 .. 16*1096) after main loop
  __shared__ short lds[18432];
  int t = threadIdx.x, wave = t >> 6, lane = t & 63;
  int wave_m = wave >> 1, wave_n = wave & 1;
  int lg = lane >> 4, l15 = lane & 15;

  f32x4 acc[4][4];
#pragma unroll
  for (int a = 0; a < 4; ++a)
#pragma unroll
    for (int b = 0; b < 4; ++b) acc[a][b] = (f32x4){0.f, 0.f, 0.f, 0.f};

  const short* A = at_t + (size_t)bm * 128 * 512;
  const short* B = bt_t + (size_t)bn * 128 * 512;

  for (int k0 = 0; k0 < 512; k0 += 64) {
    float4 av[4], bv[4];
#pragma unroll
    for (int h = 0; h < 4; ++h) {
      int e = (t + h * 256) * 8;
      int m = e >> 6, k = e & 63;
      av[h] = *reinterpret_cast<const float4*>(A + (size_t)m * 512 + k0 + k);
      bv[h] = *reinterpret_cast<const float4*>(B + (size_t)m * 512 + k0 + k);
    }
    __syncthreads();
#pragma unroll
    for (int h = 0; h < 4; ++h) {
      int e = (t + h * 256) * 8;
      int m = e >> 6, k = e & 63;
      *reinterpret_cast<float4*>(&lds[m * 72 + k]) = av[h];
      *reinterpret_cast<float4*>(&lds[9216 + m * 72 + k]) = bv[h];
    }
    __syncthreads();
#pragma unroll
    for (int ks = 0; ks < 2; ++ks) {
      int kk = ks * 32 + lg * 8;
      bf16x8 af[4], bfr[4];
#pragma unroll
      for (int f = 0; f < 4; ++f) {
        int mm = wave_m * 64 + f * 16 + l15;
        af[f] = *reinterpret_cast<const bf16x8*>(&lds[mm * 72 + kk]);
        int nn = wave_n * 64 + f * 16 + l15;
        bfr[f] = *reinterpret_cast<const bf16x8*>(&lds[9216 + nn * 72 + kk]);
      }
#pragma unroll
      for (int fm = 0; fm < 4; ++fm)
#pragma unroll
        for (int fn = 0; fn < 4; ++fn)
          acc[fm][fn] = __builtin_amdgcn_mfma_f32_16x16x32_bf16(
              af[fm], bfr[fn], acc[fm][fn], 0, 0, 0);
    }
  }
  __syncthreads();  // all waves done reading A/B tiles

  // write op tile (scaled, bf16) into P[pair][cd]; pair stride 1096,
  // cd physical slot = (cd>>7)*136 + (cd&127)
  const float inv_s = 1.0f / 512.0f;
#pragma unroll
  for (int fm = 0; fm < 4; ++fm)
#pragma unroll
    for (int fn = 0; fn < 4; ++fn)
#pragma unroll
      for (int r = 0; r < 4; ++r) {
        int m = wave_m * 64 + fm * 16 + lg * 4 + r;
        int n = wave_n * 64 + fn * 16 + l15;
        int pair = ((m >> 5) << 2) | (n >> 5);
        int cd = ((m & 31) << 5) | (n & 31);
        int slot = pair * 1096 + (cd >> 7) * 136 + (cd & 127);
        lds[slot] = f2bs(acc[fm][fn][r] * inv_s);
      }
  __syncthreads();

  // projection: P(16x1024) @ wo_t^T -> 16 x 128; wave handles e in [wave*32,+32)
  f32x4 pacc[2];
  pacc[0] = (f32x4){0.f, 0.f, 0.f, 0.f};
  pacc[1] = (f32x4){0.f, 0.f, 0.f, 0.f};
  for (int c0 = 0; c0 < 1024; c0 += 32) {
    int kk = c0 + lg * 8;
    bf16x8 pa = *reinterpret_cast<const bf16x8*>(
        &lds[l15 * 1096 + (kk >> 7) * 136 + (kk & 127)]);
#pragma unroll
    for (int f = 0; f < 2; ++f) {
      int n = wave * 32 + f * 16 + l15;
      bf16x8 pb = *reinterpret_cast<const bf16x8*>(wo_t + (size_t)n * 1024 + kk);
      pacc[f] = __builtin_amdgcn_mfma_f32_16x16x32_bf16(pa, pb, pacc[f], 0, 0, 0);
    }
  }
#pragma unroll
  for (int f = 0; f < 2; ++f)
#pragma unroll
    for (int r = 0; r < 4; ++r) {
      int pair = (lg << 2) + r;
      int e = wave * 32 + f * 16 + l15;
      int gi = bm * 4 + (pair >> 2), gj = bn * 4 + (pair & 3);
      size_t addr = ((size_t)gi * N_DIM + gj) * CZ + e;
      z1[addr] = z0[addr] + pacc[f][r] + bo[e];
    }
}

// ---------------------------------------------------------------------------
extern "C" void kernel_launch(void* const* d_in, const int* in_sizes, int n_in,
                              void* d_out, int out_size, void* d_ws, size_t ws_size,
                              hipStream_t stream) {
  const float* m0 = (const float*)d_in[0];
  const float* z0 = (const float*)d_in[1];
  const float* pwa_nm_w = (const float*)d_in[2];
  const float* pwa_nm_b = (const float*)d_in[3];
  const float* pwa_nz_w = (const float*)d_in[4];
  const float* pwa_nz_b = (const float*)d_in[5];
  const float* pwa_wm = (const float*)d_in[6];
  const float* pwa_wg = (const float*)d_in[7];
  const float* pwa_wz = (const float*)d_in[8];
  const float* pwa_wo = (const float*)d_in[9];
  const float* tr_nw = (const float*)d_in[10];
  const float* tr_nb = (const float*)d_in[11];
  const float* tr_w1 = (const float*)d_in[12];
  const float* tr_w2 = (const float*)d_in[13];
  const float* tr_w3 = (const float*)d_in[14];
  const float* opm_nw = (const float*)d_in[15];
  const float* opm_nb = (const float*)d_in[16];
  const float* opm_wa = (const float*)d_in[17];
  const float* opm_wb = (const float*)d_in[18];
  const float* opm_wo = (const float*)d_in[19];
  const float* opm_bo = (const float*)d_in[20];

  char* ws = (char*)d_ws;
  bf16* mn = (bf16*)(ws);                        // 25,165,824 B
  float* wbuf = (float*)(ws + 25165824);         //  4,718,592 B
  bf16* v = (bf16*)(ws + 29884416);              // 100,663,296 B
  bf16* o = (bf16*)(ws + 130547712);             // 100,663,296 B
  // reuse dead v region after k_ogemm:
  short* at_t = (short*)(ws + 29884416);         // 12,582,912 B
  short* bt_t = (short*)(ws + 42467328);         // 12,582,912 B
  short* wo_t = (short*)(ws + 55050240);         //    262,144 B

  float* m_out = (float*)d_out;
  float* z1 = m_out + (size_t)S_DIM * N_DIM * CM;

  k_ln_m<<<49152, 256, 0, stream>>>(m0, pwa_nm_w, pwa_nm_b, mn);
  k_zb<<<36864, 256, 0, stream>>>(z0, pwa_nz_w, pwa_nz_b, pwa_wz, wbuf);
  k_softmax<<<3072, 128, 0, stream>>>(wbuf);
  k_vgemm<<<3072, 256, 0, stream>>>(mn, pwa_wm, v);
  k_ogemm<<<dim3(1536, 8), 256, 0, stream>>>(wbuf, v, o);
  k_pwa_out<<<3072, 256, 0, stream>>>(mn, o, m0, pwa_wg, pwa_wo, m_out);
  k_wot<<<32, 256, 0, stream>>>(opm_wo, wo_t);
  k_transition<<<3072, 256, 0, stream>>>(tr_nw, tr_nb, tr_w1, tr_w2, tr_w3, m_out);
  k_opm_ab<<<3072, 256, 0, stream>>>(m_out, opm_nw, opm_nb, opm_wa, opm_wb, at_t, bt_t);
  k_opm<<<dim3(96, 96), 256, 0, stream>>>(at_t, bt_t, wo_t, opm_bo, z0, z1);
}

// Round 3
// 1711.801 us; speedup vs baseline: 2.9453x; 1.6068x over previous
//
#include <hip/hip_runtime.h>
#include <hip/hip_bf16.h>

#define S_DIM 512
#define N_DIM 384
#define CM 64
#define CZ 128
#define HEADS 8
#define DH 32
#define HD 256

typedef __hip_bfloat16 bf16;
typedef __attribute__((ext_vector_type(8))) short bf16x8;
typedef __attribute__((ext_vector_type(4))) float f32x4;

__device__ __forceinline__ float bf2f(bf16 x) { return __bfloat162float(x); }
__device__ __forceinline__ bf16 f2bf(float x) { return __float2bfloat16(x); }
__device__ __forceinline__ short f2bs(float x) {
  bf16 h = __float2bfloat16(x);
  return *reinterpret_cast<short*>(&h);
}

typedef __attribute__((address_space(3))) unsigned int lds_u32;
typedef __attribute__((address_space(1))) const unsigned int gbl_u32;
__device__ __forceinline__ void gl_lds16(const void* g, void* l) {
  __builtin_amdgcn_global_load_lds((gbl_u32*)g, (lds_u32*)l, 16, 0, 0);
}

// ---------------- LayerNorm of m0 -> mn (bf16) ------------------------------
__global__ __launch_bounds__(256) void k_ln_m(const float* __restrict__ m,
                                              const float* __restrict__ w,
                                              const float* __restrict__ b,
                                              bf16* __restrict__ mn) {
  int row = blockIdx.x * 4 + (threadIdx.x >> 6);
  int lane = threadIdx.x & 63;
  float x = m[(size_t)row * CM + lane];
  float s = x, sq = x * x;
#pragma unroll
  for (int off = 32; off; off >>= 1) {
    s += __shfl_xor(s, off);
    sq += __shfl_xor(sq, off);
  }
  float mu = s * (1.0f / CM);
  float var = sq * (1.0f / CM) - mu * mu;
  float rs = rsqrtf(var + 1e-5f);
  mn[(size_t)row * CM + lane] = f2bf((x - mu) * rs * w[lane] + b[lane]);
}

// ---------------- LN(z) + pair-bias logits ---------------------------------
__global__ __launch_bounds__(256) void k_zb(const float* __restrict__ z,
                                            const float* __restrict__ w,
                                            const float* __restrict__ b,
                                            const float* __restrict__ wz,
                                            float* __restrict__ logits) {
  int row = blockIdx.x * 4 + (threadIdx.x >> 6);  // row = i*384 + j
  int lane = threadIdx.x & 63;
  const float* x = z + (size_t)row * CZ;
  float v0 = x[lane], v1 = x[lane + 64];
  float s = v0 + v1, sq = v0 * v0 + v1 * v1;
#pragma unroll
  for (int off = 32; off; off >>= 1) {
    s += __shfl_xor(s, off);
    sq += __shfl_xor(sq, off);
  }
  float mu = s * (1.0f / CZ);
  float var = sq * (1.0f / CZ) - mu * mu;
  float rs = rsqrtf(var + 1e-5f);
  float zn0 = (v0 - mu) * rs * w[lane] + b[lane];
  float zn1 = (v1 - mu) * rs * w[lane + 64] + b[lane + 64];
  int i = row / N_DIM, j = row - i * N_DIM;
  for (int h = 0; h < HEADS; ++h) {
    float p = zn0 * wz[lane * HEADS + h] + zn1 * wz[(lane + 64) * HEADS + h];
#pragma unroll
    for (int off = 32; off; off >>= 1) p += __shfl_xor(p, off);
    if (lane == 0) logits[((size_t)i * HEADS + h) * N_DIM + j] = p;
  }
}

// ---------------- softmax over j (rows of 384), in place --------------------
__global__ __launch_bounds__(128) void k_softmax(float* __restrict__ wb) {
  float* p = wb + (size_t)blockIdx.x * N_DIM;
  int t = threadIdx.x;
  float a0 = p[t], a1 = p[t + 128], a2 = p[t + 256];
  float mx = fmaxf(a0, fmaxf(a1, a2));
  __shared__ float red[2], red2[2];
#pragma unroll
  for (int off = 32; off; off >>= 1) mx = fmaxf(mx, __shfl_xor(mx, off));
  if ((t & 63) == 0) red[t >> 6] = mx;
  __syncthreads();
  mx = fmaxf(red[0], red[1]);
  float e0 = __expf(a0 - mx), e1 = __expf(a1 - mx), e2 = __expf(a2 - mx);
  float s = e0 + e1 + e2;
#pragma unroll
  for (int off = 32; off; off >>= 1) s += __shfl_xor(s, off);
  if ((t & 63) == 0) red2[t >> 6] = s;
  __syncthreads();
  float inv = 1.0f / (red2[0] + red2[1]);
  p[t] = e0 * inv;
  p[t + 128] = e1 * inv;
  p[t + 256] = e2 * inv;
}

// ---------------- v = mn @ wm, emitted transposed as vT[h][n][j] (bf16) -----
// vT row n = h*16384 + s*32 + d; within-row j pre-swizzled: col = j ^ ((n&7)<<3)
__global__ __launch_bounds__(256) void k_vgemm(const bf16* __restrict__ mn,
                                               const float* __restrict__ wm,
                                               short* __restrict__ vT) {
  int blk = blockIdx.x;
  int sblk = blk / 6, j0 = (blk % 6) * 64;
  __shared__ char smem[43008];  // al: 0..9216, bl: 9216..43008; vt overlays bl
  bf16* al = (bf16*)smem;              // [64][72]
  bf16* bl = (bf16*)(smem + 9216);     // [64][264]
  short* vt = (short*)(smem + 9216);   // [256][64] overlay (after main loop)
  int t = threadIdx.x;
  size_t rb = (size_t)sblk * N_DIM + j0;
  for (int idx = t; idx < 4096; idx += 256) {
    int r = idx >> 6, k = idx & 63;
    al[r * 72 + k] = mn[(rb + r) * CM + k];
  }
  for (int idx = t; idx < 16384; idx += 256)
    bl[(idx >> 8) * 264 + (idx & 255)] = f2bf(wm[idx]);
  __syncthreads();
  int tr = t >> 4, tc = t & 15;
  float acc[4][16];
#pragma unroll
  for (int r = 0; r < 4; ++r)
#pragma unroll
    for (int c = 0; c < 16; ++c) acc[r][c] = 0.0f;
  for (int k = 0; k < 64; ++k) {
    float a4[4];
#pragma unroll
    for (int r = 0; r < 4; ++r) a4[r] = bf2f(al[(tr * 4 + r) * 72 + k]);
#pragma unroll
    for (int c = 0; c < 16; ++c) {
      float bv = bf2f(bl[k * 264 + tc + 16 * c]);
#pragma unroll
      for (int r = 0; r < 4; ++r) acc[r][c] += a4[r] * bv;
    }
  }
  __syncthreads();  // done with bl; overlay vt
  // transpose into vt[hd][jswz]
#pragma unroll
  for (int r = 0; r < 4; ++r) {
    int jl = tr * 4 + r;
#pragma unroll
    for (int c = 0; c < 16; ++c) {
      int hd = tc + 16 * c;
      int js = jl ^ ((hd & 7) << 3);
      vt[hd * 64 + js] = f2bs(acc[r][c]);
    }
  }
  __syncthreads();
  // copy row t (128 B) to global
  {
    int h = t >> 5, d = t & 31;
    size_t gbase = ((size_t)h * 16384 + (size_t)sblk * 32 + d) * 384 + j0;
#pragma unroll
    for (int q = 0; q < 4; ++q) {
      float4 v4 = *reinterpret_cast<const float4*>(&vt[t * 64 + q * 16]);
      *reinterpret_cast<float4*>(&vT[gbase + q * 16]) = v4;
    }
  }
}

// ---------------- o = W @ V per head, MFMA (128i x 256n tiles, K=384) -------
__global__ __launch_bounds__(256, 2) void k_ogemm(const float* __restrict__ wsm,
                                                  const short* __restrict__ vT,
                                                  bf16* __restrict__ o) {
  int h = blockIdx.y;
  int ib = blockIdx.x % 3, nb = blockIdx.x / 3;
  int i0 = ib * 128;
  __shared__ char lds8[49152];  // W: 0..16384 ([128][64] bf16), VT: 16384..49152
  short* Wl = (short*)lds8;
  short* Vl = (short*)(lds8 + 16384);
  int t = threadIdx.x, wave = t >> 6, lane = t & 63;
  int lg = lane >> 4, l15 = lane & 15;
  f32x4 acc[8][4];
#pragma unroll
  for (int a = 0; a < 8; ++a)
#pragma unroll
    for (int b = 0; b < 4; ++b) acc[a][b] = (f32x4){0.f, 0.f, 0.f, 0.f};
  const short* VTb = vT + ((size_t)h * 16384 + (size_t)nb * 256) * 384;
  int wi = t >> 1, wjh = (t & 1) * 32;
  const float* wrow = wsm + (size_t)(i0 + wi) * (HEADS * N_DIM) + h * N_DIM + wjh;
  int wswz = (wi & 7) << 3;
  for (int j0 = 0; j0 < N_DIM; j0 += 64) {
    // stage VT tile via global_load_lds (linear dest, pre-swizzled source)
#pragma unroll
    for (int q = 0; q < 8; ++q) {
      int chunk = wave * 8 + q;
      int nl = chunk * 8 + (lane >> 3);
      gl_lds16(VTb + (size_t)nl * 384 + j0 + (lane & 7) * 8, Vl + chunk * 512);
    }
    // stage W (fp32 -> bf16, swizzled ds_write)
#pragma unroll
    for (int q = 0; q < 8; ++q) {
      float4 f = *reinterpret_cast<const float4*>(wrow + j0 + q * 4);
      int js = (wjh + q * 4) ^ wswz;
      short4 pk;
      pk.x = f2bs(f.x); pk.y = f2bs(f.y); pk.z = f2bs(f.z); pk.w = f2bs(f.w);
      *reinterpret_cast<short4*>(&Wl[wi * 64 + js]) = pk;
    }
    __syncthreads();
#pragma unroll
    for (int ks = 0; ks < 2; ++ks) {
      int kk2 = (ks * 32 + lg * 8) * 2;
      bf16x8 bfr[4];
#pragma unroll
      for (int fn = 0; fn < 4; ++fn) {
        int nl = wave * 64 + fn * 16 + l15;
        bfr[fn] = *reinterpret_cast<const bf16x8*>(
            lds8 + 16384 + nl * 128 + (kk2 ^ ((nl & 7) << 4)));
      }
#pragma unroll
      for (int fm = 0; fm < 8; ++fm) {
        int il = fm * 16 + l15;
        bf16x8 af = *reinterpret_cast<const bf16x8*>(
            lds8 + il * 128 + (kk2 ^ ((il & 7) << 4)));
#pragma unroll
        for (int fn = 0; fn < 4; ++fn)
          acc[fm][fn] = __builtin_amdgcn_mfma_f32_16x16x32_bf16(
              af, bfr[fn], acc[fm][fn], 0, 0, 0);
      }
    }
    __syncthreads();
  }
#pragma unroll
  for (int fm = 0; fm < 8; ++fm)
#pragma unroll
    for (int fn = 0; fn < 4; ++fn)
#pragma unroll
      for (int r = 0; r < 4; ++r) {
        int i = i0 + fm * 16 + lg * 4 + r;
        int n = nb * 256 + wave * 64 + fn * 16 + l15;
        int s = n >> 5, d = n & 31;
        o[((size_t)s * N_DIM + i) * HD + h * DH + d] = f2bf(acc[fm][fn][r]);
      }
}

// ---------------- pwa out: g=sigmoid(mn@wg); m1 = m0 + (o*g)@wo -------------
__global__ __launch_bounds__(256) void k_pwa_out(const bf16* __restrict__ mn,
                                                 const bf16* __restrict__ o,
                                                 const float* __restrict__ m0,
                                                 const float* __restrict__ wg,
                                                 const float* __restrict__ wo,
                                                 float* __restrict__ m1out) {
  int blk = blockIdx.x;
  int s = blk / 6, j0 = (blk % 6) * 64;
  __shared__ bf16 al[64][72];
  __shared__ bf16 wgl[64][264];
  __shared__ bf16 ogl[64][72];
  __shared__ bf16 wol[64][72];
  int t = threadIdx.x, tr = t >> 4, tc = t & 15;
  size_t rb = (size_t)s * N_DIM + j0;
  for (int idx = t; idx < 4096; idx += 256) {
    int r = idx >> 6, k = idx & 63;
    al[r][k] = mn[(rb + r) * CM + k];
  }
  for (int idx = t; idx < 16384; idx += 256)
    wgl[idx >> 8][idx & 255] = f2bf(wg[idx]);
  __syncthreads();
  float og[4][16];
#pragma unroll
  for (int r = 0; r < 4; ++r)
#pragma unroll
    for (int c = 0; c < 16; ++c) og[r][c] = 0.0f;
  for (int k = 0; k < 64; ++k) {
    float a4[4];
#pragma unroll
    for (int r = 0; r < 4; ++r) a4[r] = bf2f(al[tr * 4 + r][k]);
#pragma unroll
    for (int c = 0; c < 16; ++c) {
      float wv = bf2f(wgl[k][tc + 16 * c]);
#pragma unroll
      for (int r = 0; r < 4; ++r) og[r][c] += a4[r] * wv;
    }
  }
#pragma unroll
  for (int r = 0; r < 4; ++r)
#pragma unroll
    for (int c = 0; c < 16; ++c) {
      float g = 1.0f / (1.0f + __expf(-og[r][c]));
      float ov = bf2f(o[(rb + tr * 4 + r) * HD + tc + 16 * c]);
      og[r][c] = g * ov;
    }
  float outa[4][4];
#pragma unroll
  for (int r = 0; r < 4; ++r)
#pragma unroll
    for (int c = 0; c < 4; ++c) outa[r][c] = 0.0f;
  for (int kc = 0; kc < 4; ++kc) {
    __syncthreads();
#pragma unroll
    for (int r = 0; r < 4; ++r)
#pragma unroll
      for (int cc = 0; cc < 4; ++cc)
        ogl[tr * 4 + r][tc + 16 * cc] = f2bf(og[r][kc * 4 + cc]);
    for (int idx = t; idx < 4096; idx += 256) {
      int kk = idx >> 6, n = idx & 63;
      wol[kk][n] = f2bf(wo[(size_t)(kc * 64 + kk) * CM + n]);
    }
    __syncthreads();
    for (int kk = 0; kk < 64; ++kk) {
      float a4[4], b4[4];
#pragma unroll
      for (int r = 0; r < 4; ++r) a4[r] = bf2f(ogl[tr * 4 + r][kk]);
#pragma unroll
      for (int c = 0; c < 4; ++c) b4[c] = bf2f(wol[kk][tc * 4 + c]);
#pragma unroll
      for (int r = 0; r < 4; ++r)
#pragma unroll
        for (int c = 0; c < 4; ++c) outa[r][c] += a4[r] * b4[c];
    }
  }
#pragma unroll
  for (int r = 0; r < 4; ++r)
#pragma unroll
    for (int c = 0; c < 4; ++c) {
      size_t a = (rb + tr * 4 + r) * CM + tc * 4 + c;
      m1out[a] = m0[a] + outa[r][c];
    }
}

// ---------------- transition: m2 = m1 + (silu(tn@w1)*(tn@w2))@w3 ------------
__global__ __launch_bounds__(256) void k_transition(const float* __restrict__ nw,
                                                    const float* __restrict__ nb,
                                                    const float* __restrict__ w1,
                                                    const float* __restrict__ w2,
                                                    const float* __restrict__ w3,
                                                    float* __restrict__ mio) {
  size_t rb = (size_t)blockIdx.x * 64;
  __shared__ bf16 al[64][72];
  __shared__ bf16 wl[64][264];
  __shared__ bf16 hgl[64][72];
  __shared__ bf16 w3l[64][72];
  int t = threadIdx.x, tr = t >> 4, tc = t & 15;
  int wv = t >> 6, ln = t & 63;
  for (int rr = wv; rr < 64; rr += 4) {
    float x = mio[(rb + rr) * CM + ln];
    float s = x, sq = x * x;
#pragma unroll
    for (int off = 32; off; off >>= 1) {
      s += __shfl_xor(s, off);
      sq += __shfl_xor(sq, off);
    }
    float mu = s * (1.0f / CM);
    float var = sq * (1.0f / CM) - mu * mu;
    float rs = rsqrtf(var + 1e-5f);
    al[rr][ln] = f2bf((x - mu) * rs * nw[ln] + nb[ln]);
  }
  for (int idx = t; idx < 16384; idx += 256)
    wl[idx >> 8][idx & 255] = f2bf(w1[idx]);
  __syncthreads();
  float acc1[4][16], acc2[4][16];
#pragma unroll
  for (int r = 0; r < 4; ++r)
#pragma unroll
    for (int c = 0; c < 16; ++c) acc1[r][c] = 0.0f;
  for (int k = 0; k < 64; ++k) {
    float a4[4];
#pragma unroll
    for (int r = 0; r < 4; ++r) a4[r] = bf2f(al[tr * 4 + r][k]);
#pragma unroll
    for (int c = 0; c < 16; ++c) {
      float wvv = bf2f(wl[k][tc + 16 * c]);
#pragma unroll
      for (int r = 0; r < 4; ++r) acc1[r][c] += a4[r] * wvv;
    }
  }
  __syncthreads();
  for (int idx = t; idx < 16384; idx += 256)
    wl[idx >> 8][idx & 255] = f2bf(w2[idx]);
  __syncthreads();
#pragma unroll
  for (int r = 0; r < 4; ++r)
#pragma unroll
    for (int c = 0; c < 16; ++c) acc2[r][c] = 0.0f;
  for (int k = 0; k < 64; ++k) {
    float a4[4];
#pragma unroll
    for (int r = 0; r < 4; ++r) a4[r] = bf2f(al[tr * 4 + r][k]);
#pragma unroll
    for (int c = 0; c < 16; ++c) {
      float wvv = bf2f(wl[k][tc + 16 * c]);
#pragma unroll
      for (int r = 0; r < 4; ++r) acc2[r][c] += a4[r] * wvv;
    }
  }
#pragma unroll
  for (int r = 0; r < 4; ++r)
#pragma unroll
    for (int c = 0; c < 16; ++c) {
      float x = acc1[r][c];
      acc1[r][c] = (x / (1.0f + __expf(-x))) * acc2[r][c];
    }
  float outa[4][4];
#pragma unroll
  for (int r = 0; r < 4; ++r)
#pragma unroll
    for (int c = 0; c < 4; ++c) outa[r][c] = 0.0f;
  for (int kc = 0; kc < 4; ++kc) {
    __syncthreads();
#pragma unroll
    for (int r = 0; r < 4; ++r)
#pragma unroll
      for (int cc = 0; cc < 4; ++cc)
        hgl[tr * 4 + r][tc + 16 * cc] = f2bf(acc1[r][kc * 4 + cc]);
    for (int idx = t; idx < 4096; idx += 256) {
      int kk = idx >> 6, n = idx & 63;
      w3l[kk][n] = f2bf(w3[(size_t)(kc * 64 + kk) * CM + n]);
    }
    __syncthreads();
    for (int kk = 0; kk < 64; ++kk) {
      float a4[4], b4[4];
#pragma unroll
      for (int r = 0; r < 4; ++r) a4[r] = bf2f(hgl[tr * 4 + r][kk]);
#pragma unroll
      for (int c = 0; c < 4; ++c) b4[c] = bf2f(w3l[kk][tc * 4 + c]);
#pragma unroll
      for (int r = 0; r < 4; ++r)
#pragma unroll
        for (int c = 0; c < 4; ++c) outa[r][c] += a4[r] * b4[c];
    }
  }
#pragma unroll
  for (int r = 0; r < 4; ++r)
#pragma unroll
    for (int c = 0; c < 4; ++c) {
      size_t a = (rb + tr * 4 + r) * CM + tc * 4 + c;
      mio[a] = mio[a] + outa[r][c];
    }
}

// ---------------- opm a/b: LN(m2)@wa/wb -> bf16 [m][k], pre-swizzled --------
// m = i*32+c (rows 12288), k = s (512); phys col = (k&~63)|((k&63)^((m&7)<<3))
__global__ __launch_bounds__(256) void k_opm_ab(const float* __restrict__ m2,
                                                const float* __restrict__ nw,
                                                const float* __restrict__ nb,
                                                const float* __restrict__ wa,
                                                const float* __restrict__ wb,
                                                short* __restrict__ at_t,
                                                short* __restrict__ bt_t) {
  int bix = blockIdx.x;
  int sg = bix / N_DIM;
  int i = bix - sg * N_DIM;
  __shared__ float on[64][65];
  __shared__ float wl[2][64][36];
  __shared__ float tl[2][32][65];
  int t = threadIdx.x, w = t >> 6, lane = t & 63;
  float gw = nw[lane], gb = nb[lane];
  for (int rr = 0; rr < 16; ++rr) {
    int sl = w * 16 + rr;
    float x = m2[((size_t)(sg * 64 + sl) * N_DIM + i) * CM + lane];
    float s = x, sq = x * x;
#pragma unroll
    for (int off = 32; off; off >>= 1) {
      s += __shfl_xor(s, off);
      sq += __shfl_xor(sq, off);
    }
    float mu = s * (1.0f / CM);
    float var = sq * (1.0f / CM) - mu * mu;
    float rs = rsqrtf(var + 1e-5f);
    on[sl][lane] = (x - mu) * rs * gw + gb;
  }
  for (int idx = t; idx < 2048; idx += 256) {
    int k = idx >> 5, c = idx & 31;
    wl[0][k][c] = wa[idx];
    wl[1][k][c] = wb[idx];
  }
  __syncthreads();
  int s = t >> 2, c0 = (t & 3) * 8;
  float accA[8], accB[8];
#pragma unroll
  for (int j = 0; j < 8; ++j) { accA[j] = 0.0f; accB[j] = 0.0f; }
  for (int k = 0; k < 64; ++k) {
    float ov = on[s][k];
#pragma unroll
    for (int j = 0; j < 8; ++j) {
      accA[j] += ov * wl[0][k][c0 + j];
      accB[j] += ov * wl[1][k][c0 + j];
    }
  }
#pragma unroll
  for (int j = 0; j < 8; ++j) {
    tl[0][c0 + j][s] = accA[j];
    tl[1][c0 + j][s] = accB[j];
  }
  __syncthreads();
  size_t obase = (size_t)i * 32 * 512 + (size_t)sg * 64;
  for (int idx = t; idx < 2048; idx += 256) {
    int c = idx >> 6, s2 = idx & 63;
    int col = s2 ^ ((c & 7) << 3);   // pre-swizzle for k_opm's LDS reads
    at_t[obase + (size_t)c * 512 + col] = f2bs(tl[0][c][s2]);
    bt_t[obase + (size_t)c * 512 + col] = f2bs(tl[1][c][s2]);
  }
}

// ---------------- wo_f: fragment-packed wo (bf16) ---------------------------
// wo_f[((eblk*32 + kc)*64 + lane)*8 + j] = wo[(kc*32 + (lane>>4)*8 + j)*128 + eblk*16 + (lane&15)]
__global__ __launch_bounds__(256) void k_wot(const float* __restrict__ wo,
                                             short* __restrict__ wo_f) {
  int tg = blockIdx.x * 256 + threadIdx.x;   // 64 blocks
  int frag = tg >> 6, lane = tg & 63;
  int eblk = frag >> 5, kc = frag & 31;
  int e = eblk * 16 + (lane & 15);
  int kbase = kc * 32 + (lane >> 4) * 8;
  short out[8];
#pragma unroll
  for (int j = 0; j < 8; ++j) out[j] = f2bs(wo[(size_t)(kbase + j) * CZ + e]);
  *reinterpret_cast<float4*>(&wo_f[(size_t)tg * 8]) =
      *reinterpret_cast<const float4*>(out);
}

// ---------------- OPM via MFMA: 256x256 op tile (K=512) + fused projection --
__global__ __launch_bounds__(512, 2) void k_opm(const short* __restrict__ at_t,
                                                const short* __restrict__ bt_t,
                                                const short* __restrict__ wo_f,
                                                const float* __restrict__ bo,
                                                const float* __restrict__ z0,
                                                float* __restrict__ z1) {
  // bijective XCD-chunked mapping: each XCD owns 6 bm x 48 bn, bn-major
  int g = blockIdx.x;
  int xcd = g & 7, u = g >> 3;
  int bm = xcd * 6 + (u % 6), bn = u / 6;
  __shared__ __align__(16) char lds8[65536];  // A: 0..32K, B: 32K..64K; P overlays
  int t = threadIdx.x, wave = t >> 6, lane = t & 63;
  int wm = wave >> 2, wn = wave & 3;
  int lg = lane >> 4, l15 = lane & 15;
  f32x4 acc[8][4];
#pragma unroll
  for (int a = 0; a < 8; ++a)
#pragma unroll
    for (int b = 0; b < 4; ++b) acc[a][b] = (f32x4){0.f, 0.f, 0.f, 0.f};
  const short* A = at_t + (size_t)bm * 256 * 512;
  const short* B = bt_t + (size_t)bn * 256 * 512;
  short* ldsA = (short*)lds8;
  short* ldsB = (short*)(lds8 + 32768);

  for (int k0 = 0; k0 < 512; k0 += 64) {
#pragma unroll
    for (int q = 0; q < 4; ++q) {
      int chunk = wave * 4 + q;            // 32 chunks of 8 rows
      int ml = chunk * 8 + (lane >> 3);
      size_t goff = (size_t)ml * 512 + k0 + (lane & 7) * 8;
      gl_lds16(A + goff, ldsA + chunk * 512);
      gl_lds16(B + goff, ldsB + chunk * 512);
    }
    __syncthreads();
#pragma unroll
    for (int ks = 0; ks < 2; ++ks) {
      int kk2 = (ks * 32 + lg * 8) * 2;
      bf16x8 bfr[4];
#pragma unroll
      for (int fn = 0; fn < 4; ++fn) {
        int nl = wn * 64 + fn * 16 + l15;
        bfr[fn] = *reinterpret_cast<const bf16x8*>(
            lds8 + 32768 + nl * 128 + (kk2 ^ ((nl & 7) << 4)));
      }
#pragma unroll
      for (int fm = 0; fm < 8; ++fm) {
        int ml = wm * 128 + fm * 16 + l15;
        bf16x8 af = *reinterpret_cast<const bf16x8*>(
            lds8 + ml * 128 + (kk2 ^ ((ml & 7) << 4)));
#pragma unroll
        for (int fn = 0; fn < 4; ++fn)
          acc[fm][fn] = __builtin_amdgcn_mfma_f32_16x16x32_bf16(
              af, bfr[fn], acc[fm][fn], 0, 0, 0);
      }
    }
    __syncthreads();
  }

  // 4 chunks of 16 pairs; P[16][1032] bf16 overlays lds8
  short* P = (short*)lds8;
  const float inv_s = 1.0f / 512.0f;
#pragma unroll
  for (int q = 0; q < 4; ++q) {
    if (wm == (q >> 1)) {
      int fmb = (q & 1) * 4;
#pragma unroll
      for (int fm2 = 0; fm2 < 4; ++fm2) {
        int fm = fmb + fm2;
#pragma unroll
        for (int fn = 0; fn < 4; ++fn)
#pragma unroll
          for (int r = 0; r < 4; ++r) {
            int m = wm * 128 + fm * 16 + lg * 4 + r;
            int n = wn * 64 + fn * 16 + l15;
            int prow = ((m >> 5) & 1) * 8 + (n >> 5);
            int cd = ((m & 31) << 5) | (n & 31);
            P[prow * 1032 + cd] = f2bs(acc[fm][fn][r] * inv_s);
          }
      }
    }
    __syncthreads();
    f32x4 pacc = (f32x4){0.f, 0.f, 0.f, 0.f};
    int e = wave * 16 + l15;
    for (int c0 = 0; c0 < 1024; c0 += 32) {
      bf16x8 pa = *reinterpret_cast<const bf16x8*>(P + l15 * 1032 + c0 + lg * 8);
      bf16x8 pb = *reinterpret_cast<const bf16x8*>(
          wo_f + ((size_t)(wave * 32 + (c0 >> 5)) * 64 + lane) * 8);
      pacc = __builtin_amdgcn_mfma_f32_16x16x32_bf16(pa, pb, pacc, 0, 0, 0);
    }
    float bov = bo[e];
#pragma unroll
    for (int r = 0; r < 4; ++r) {
      int pair = q * 16 + lg * 4 + r;
      int gi = bm * 8 + (pair >> 3), gj = bn * 8 + (pair & 7);
      size_t addr = ((size_t)gi * N_DIM + gj) * CZ + e;
      z1[addr] = z0[addr] + pacc[r] + bov;
    }
    __syncthreads();
  }
}

// ---------------------------------------------------------------------------
extern "C" void kernel_launch(void* const* d_in, const int* in_sizes, int n_in,
                              void* d_out, int out_size, void* d_ws, size_t ws_size,
                              hipStream_t stream) {
  const float* m0 = (const float*)d_in[0];
  const float* z0 = (const float*)d_in[1];
  const float* pwa_nm_w = (const float*)d_in[2];
  const float* pwa_nm_b = (const float*)d_in[3];
  const float* pwa_nz_w = (const float*)d_in[4];
  const float* pwa_nz_b = (const float*)d_in[5];
  const float* pwa_wm = (const float*)d_in[6];
  const float* pwa_wg = (const float*)d_in[7];
  const float* pwa_wz = (const float*)d_in[8];
  const float* pwa_wo = (const float*)d_in[9];
  const float* tr_nw = (const float*)d_in[10];
  const float* tr_nb = (const float*)d_in[11];
  const float* tr_w1 = (const float*)d_in[12];
  const float* tr_w2 = (const float*)d_in[13];
  const float* tr_w3 = (const float*)d_in[14];
  const float* opm_nw = (const float*)d_in[15];
  const float* opm_nb = (const float*)d_in[16];
  const float* opm_wa = (const float*)d_in[17];
  const float* opm_wb = (const float*)d_in[18];
  const float* opm_wo = (const float*)d_in[19];
  const float* opm_bo = (const float*)d_in[20];

  char* ws = (char*)d_ws;
  bf16* mn = (bf16*)(ws);                        // 25,165,824 B
  float* wbuf = (float*)(ws + 25165824);         //  4,718,592 B
  short* vT = (short*)(ws + 29884416);           // 100,663,296 B
  bf16* o = (bf16*)(ws + 130547712);             // 100,663,296 B
  // reuse dead vT region after k_ogemm:
  short* at_t = (short*)(ws + 29884416);         // 12,582,912 B
  short* bt_t = (short*)(ws + 42467328);         // 12,582,912 B
  short* wo_f = (short*)(ws + 55050240);         //    262,144 B

  float* m_out = (float*)d_out;
  float* z1 = m_out + (size_t)S_DIM * N_DIM * CM;

  k_ln_m<<<49152, 256, 0, stream>>>(m0, pwa_nm_w, pwa_nm_b, mn);
  k_zb<<<36864, 256, 0, stream>>>(z0, pwa_nz_w, pwa_nz_b, pwa_wz, wbuf);
  k_softmax<<<3072, 128, 0, stream>>>(wbuf);
  k_vgemm<<<3072, 256, 0, stream>>>(mn, pwa_wm, vT);
  k_ogemm<<<dim3(192, 8), 256, 0, stream>>>(wbuf, vT, o);
  k_pwa_out<<<3072, 256, 0, stream>>>(mn, o, m0, pwa_wg, pwa_wo, m_out);
  k_wot<<<64, 256, 0, stream>>>(opm_wo, wo_f);
  k_transition<<<3072, 256, 0, stream>>>(tr_nw, tr_nb, tr_w1, tr_w2, tr_w3, m_out);
  k_opm_ab<<<3072, 256, 0, stream>>>(m_out, opm_nw, opm_nb, opm_wa, opm_wb, at_t, bt_t);
  k_opm<<<2304, 512, 0, stream>>>(at_t, bt_t, wo_f, opm_bo, z0, z1);
}

// Round 4
// 1093.316 us; speedup vs baseline: 4.6114x; 1.5657x over previous
//
#include <hip/hip_runtime.h>
#include <hip/hip_bf16.h>

#define S_DIM 512
#define N_DIM 384
#define CM 64
#define CZ 128
#define HEADS 8
#define DH 32
#define HD 256

typedef __hip_bfloat16 bf16;
typedef __attribute__((ext_vector_type(8))) short bf16x8;
typedef __attribute__((ext_vector_type(4))) float f32x4;

__device__ __forceinline__ float bf2f(bf16 x) { return __bfloat162float(x); }
__device__ __forceinline__ bf16 f2bf(float x) { return __float2bfloat16(x); }
__device__ __forceinline__ short f2bs(float x) {
  bf16 h = __float2bfloat16(x);
  return *reinterpret_cast<short*>(&h);
}

typedef __attribute__((address_space(3))) unsigned int lds_u32;
typedef __attribute__((address_space(1))) const unsigned int gbl_u32;
__device__ __forceinline__ void gl_lds16(const void* g, void* l) {
  __builtin_amdgcn_global_load_lds((gbl_u32*)g, (lds_u32*)l, 16, 0, 0);
}

// ---------------- weight prep: pack [K][N] fp32 -> bf16 MFMA B-fragments ----
// frag (ks,nf): lane l holds W[ks*32+(l>>4)*8+j][nf*16+(l&15)], j=0..7
__global__ __launch_bounds__(256) void k_wprep(const float* __restrict__ wm,
                                               const float* __restrict__ wg,
                                               const float* __restrict__ w1,
                                               const float* __restrict__ w2,
                                               const float* __restrict__ wpo,
                                               const float* __restrict__ w3,
                                               short* __restrict__ dst) {
  int widx = blockIdx.x >> 3;
  const float* src;
  int N;
  if (widx == 0) { src = wm; N = 256; }
  else if (widx == 1) { src = wg; N = 256; }
  else if (widx == 2) { src = w1; N = 256; }
  else if (widx == 3) { src = w2; N = 256; }
  else if (widx == 4) { src = wpo; N = 64; }
  else { src = w3; N = 64; }
  int NF = N >> 4;
  int tg = ((blockIdx.x & 7) << 8) | threadIdx.x;
  int frag = tg >> 6, lane = tg & 63, lg = lane >> 4, l15 = lane & 15;
  int ks = frag / NF, nf = frag - ks * NF;
  short out[8];
#pragma unroll
  for (int j = 0; j < 8; ++j)
    out[j] = f2bs(src[(size_t)(ks * 32 + lg * 8 + j) * N + nf * 16 + l15]);
  *reinterpret_cast<float4*>(&dst[((size_t)widx << 14) + ((size_t)tg << 3)]) =
      *reinterpret_cast<const float4*>(out);
}

// ---------------- LayerNorm of m0 -> mn (bf16) ------------------------------
__global__ __launch_bounds__(256) void k_ln_m(const float* __restrict__ m,
                                              const float* __restrict__ w,
                                              const float* __restrict__ b,
                                              bf16* __restrict__ mn) {
  int row = blockIdx.x * 4 + (threadIdx.x >> 6);
  int lane = threadIdx.x & 63;
  float x = m[(size_t)row * CM + lane];
  float s = x, sq = x * x;
#pragma unroll
  for (int off = 32; off; off >>= 1) {
    s += __shfl_xor(s, off);
    sq += __shfl_xor(sq, off);
  }
  float mu = s * (1.0f / CM);
  float var = sq * (1.0f / CM) - mu * mu;
  float rs = rsqrtf(var + 1e-5f);
  mn[(size_t)row * CM + lane] = f2bf((x - mu) * rs * w[lane] + b[lane]);
}

// ---------------- LN(z) + pair-bias logits ---------------------------------
__global__ __launch_bounds__(256) void k_zb(const float* __restrict__ z,
                                            const float* __restrict__ w,
                                            const float* __restrict__ b,
                                            const float* __restrict__ wz,
                                            float* __restrict__ logits) {
  int row = blockIdx.x * 4 + (threadIdx.x >> 6);  // row = i*384 + j
  int lane = threadIdx.x & 63;
  const float* x = z + (size_t)row * CZ;
  float v0 = x[lane], v1 = x[lane + 64];
  float s = v0 + v1, sq = v0 * v0 + v1 * v1;
#pragma unroll
  for (int off = 32; off; off >>= 1) {
    s += __shfl_xor(s, off);
    sq += __shfl_xor(sq, off);
  }
  float mu = s * (1.0f / CZ);
  float var = sq * (1.0f / CZ) - mu * mu;
  float rs = rsqrtf(var + 1e-5f);
  float zn0 = (v0 - mu) * rs * w[lane] + b[lane];
  float zn1 = (v1 - mu) * rs * w[lane + 64] + b[lane + 64];
  int i = row / N_DIM, j = row - i * N_DIM;
  for (int h = 0; h < HEADS; ++h) {
    float p = zn0 * wz[lane * HEADS + h] + zn1 * wz[(lane + 64) * HEADS + h];
#pragma unroll
    for (int off = 32; off; off >>= 1) p += __shfl_xor(p, off);
    if (lane == 0) logits[((size_t)i * HEADS + h) * N_DIM + j] = p;
  }
}

// ---------------- softmax over j (rows of 384), in place --------------------
__global__ __launch_bounds__(128) void k_softmax(float* __restrict__ wb) {
  float* p = wb + (size_t)blockIdx.x * N_DIM;
  int t = threadIdx.x;
  float a0 = p[t], a1 = p[t + 128], a2 = p[t + 256];
  float mx = fmaxf(a0, fmaxf(a1, a2));
  __shared__ float red[2], red2[2];
#pragma unroll
  for (int off = 32; off; off >>= 1) mx = fmaxf(mx, __shfl_xor(mx, off));
  if ((t & 63) == 0) red[t >> 6] = mx;
  __syncthreads();
  mx = fmaxf(red[0], red[1]);
  float e0 = __expf(a0 - mx), e1 = __expf(a1 - mx), e2 = __expf(a2 - mx);
  float s = e0 + e1 + e2;
#pragma unroll
  for (int off = 32; off; off >>= 1) s += __shfl_xor(s, off);
  if ((t & 63) == 0) red2[t >> 6] = s;
  __syncthreads();
  float inv = 1.0f / (red2[0] + red2[1]);
  p[t] = e0 * inv;
  p[t + 128] = e1 * inv;
  p[t + 256] = e2 * inv;
}

// ---------------- v = mn @ wm via MFMA, emit vT[h][n][j] pre-swizzled -------
__global__ __launch_bounds__(256, 1) void k_vgemm(const bf16* __restrict__ mn,
                                                  const short* __restrict__ wm_f,
                                                  short* __restrict__ vT) {
  int blk = blockIdx.x;
  int sblk = blk / 6, j0 = (blk % 6) * 64;
  __shared__ short vt[256 * 64];
  int t = threadIdx.x, wave = t >> 6, lane = t & 63;
  int lg = lane >> 4, l15 = lane & 15;
  size_t rb = (size_t)sblk * N_DIM + j0;
  int rw0 = wave * 16;
  const short* mrow = (const short*)mn + (rb + rw0 + l15) * CM;
  bf16x8 a0 = *reinterpret_cast<const bf16x8*>(mrow + lg * 8);
  bf16x8 a1 = *reinterpret_cast<const bf16x8*>(mrow + 32 + lg * 8);
  f32x4 acc[16];
#pragma unroll
  for (int nf = 0; nf < 16; ++nf) acc[nf] = (f32x4){0.f, 0.f, 0.f, 0.f};
#pragma unroll
  for (int nf = 0; nf < 16; ++nf) {
    bf16x8 b0 = *reinterpret_cast<const bf16x8*>(wm_f + ((size_t)nf * 64 + lane) * 8);
    bf16x8 b1 = *reinterpret_cast<const bf16x8*>(wm_f + ((size_t)(16 + nf) * 64 + lane) * 8);
    acc[nf] = __builtin_amdgcn_mfma_f32_16x16x32_bf16(a0, b0, acc[nf], 0, 0, 0);
    acc[nf] = __builtin_amdgcn_mfma_f32_16x16x32_bf16(a1, b1, acc[nf], 0, 0, 0);
  }
#pragma unroll
  for (int nf = 0; nf < 16; ++nf)
#pragma unroll
    for (int r = 0; r < 4; ++r) {
      int jl = rw0 + lg * 4 + r;
      int hd = nf * 16 + l15;
      int js = jl ^ ((hd & 7) << 3);
      vt[hd * 64 + js] = f2bs(acc[nf][r]);
    }
  __syncthreads();
  int h = t >> 5, d = t & 31;
  size_t gbase = ((size_t)h * 16384 + (size_t)sblk * 32 + d) * 384 + j0;
#pragma unroll
  for (int q = 0; q < 8; ++q)
    *reinterpret_cast<float4*>(&vT[gbase + q * 8]) =
        *reinterpret_cast<const float4*>(&vt[t * 64 + q * 8]);
}

// ---------------- o = W @ V per head, MFMA (128i x 256n tiles, K=384) -------
__global__ __launch_bounds__(256, 2) void k_ogemm(const float* __restrict__ wsm,
                                                  const short* __restrict__ vT,
                                                  bf16* __restrict__ o) {
  int h = blockIdx.y;
  int ib = blockIdx.x % 3, nb = blockIdx.x / 3;
  int i0 = ib * 128;
  __shared__ char lds8[49152];  // W: 0..16384 ([128][64] bf16), VT: 16384..49152
  short* Wl = (short*)lds8;
  short* Vl = (short*)(lds8 + 16384);
  int t = threadIdx.x, wave = t >> 6, lane = t & 63;
  int lg = lane >> 4, l15 = lane & 15;
  f32x4 acc[8][4];
#pragma unroll
  for (int a = 0; a < 8; ++a)
#pragma unroll
    for (int b = 0; b < 4; ++b) acc[a][b] = (f32x4){0.f, 0.f, 0.f, 0.f};
  const short* VTb = vT + ((size_t)h * 16384 + (size_t)nb * 256) * 384;
  int wi = t >> 1, wjh = (t & 1) * 32;
  const float* wrow = wsm + (size_t)(i0 + wi) * (HEADS * N_DIM) + h * N_DIM + wjh;
  int wswz = (wi & 7) << 3;
  for (int j0 = 0; j0 < N_DIM; j0 += 64) {
#pragma unroll
    for (int q = 0; q < 8; ++q) {
      int chunk = wave * 8 + q;
      int nl = chunk * 8 + (lane >> 3);
      gl_lds16(VTb + (size_t)nl * 384 + j0 + (lane & 7) * 8, Vl + chunk * 512);
    }
#pragma unroll
    for (int q = 0; q < 8; ++q) {
      float4 f = *reinterpret_cast<const float4*>(wrow + j0 + q * 4);
      int js = (wjh + q * 4) ^ wswz;
      short4 pk;
      pk.x = f2bs(f.x); pk.y = f2bs(f.y); pk.z = f2bs(f.z); pk.w = f2bs(f.w);
      *reinterpret_cast<short4*>(&Wl[wi * 64 + js]) = pk;
    }
    __syncthreads();
#pragma unroll
    for (int ks = 0; ks < 2; ++ks) {
      int kk2 = (ks * 32 + lg * 8) * 2;
      bf16x8 bfr[4];
#pragma unroll
      for (int fn = 0; fn < 4; ++fn) {
        int nl = wave * 64 + fn * 16 + l15;
        bfr[fn] = *reinterpret_cast<const bf16x8*>(
            lds8 + 16384 + nl * 128 + (kk2 ^ ((nl & 7) << 4)));
      }
#pragma unroll
      for (int fm = 0; fm < 8; ++fm) {
        int il = fm * 16 + l15;
        bf16x8 af = *reinterpret_cast<const bf16x8*>(
            lds8 + il * 128 + (kk2 ^ ((il & 7) << 4)));
#pragma unroll
        for (int fn = 0; fn < 4; ++fn)
          acc[fm][fn] = __builtin_amdgcn_mfma_f32_16x16x32_bf16(
              af, bfr[fn], acc[fm][fn], 0, 0, 0);
      }
    }
    __syncthreads();
  }
#pragma unroll
  for (int fm = 0; fm < 8; ++fm)
#pragma unroll
    for (int fn = 0; fn < 4; ++fn)
#pragma unroll
      for (int r = 0; r < 4; ++r) {
        int i = i0 + fm * 16 + lg * 4 + r;
        int n = nb * 256 + wave * 64 + fn * 16 + l15;
        int s = n >> 5, d = n & 31;
        o[((size_t)s * N_DIM + i) * HD + h * DH + d] = f2bf(acc[fm][fn][r]);
      }
}

// ---------------- pwa out via MFMA: g=sigmoid(mn@wg); m1 = m0 + (o*g)@wo ----
__global__ __launch_bounds__(256, 1) void k_pwa_out(const bf16* __restrict__ mn,
                                                    const bf16* __restrict__ o,
                                                    const float* __restrict__ m0,
                                                    const short* __restrict__ wg_f,
                                                    const short* __restrict__ wpo_f,
                                                    float* __restrict__ m1out) {
  int blk = blockIdx.x;
  int sblk = blk / 6, j0 = (blk % 6) * 64;
  __shared__ __align__(16) char hlds[32768];
  int t = threadIdx.x, wave = t >> 6, lane = t & 63;
  int lg = lane >> 4, l15 = lane & 15;
  size_t rb = (size_t)sblk * N_DIM + j0 + wave * 16;
  const short* mrow = (const short*)mn + (rb + l15) * CM;
  bf16x8 a0 = *reinterpret_cast<const bf16x8*>(mrow + lg * 8);
  bf16x8 a1 = *reinterpret_cast<const bf16x8*>(mrow + 32 + lg * 8);
  f32x4 acc[16];
#pragma unroll
  for (int nf = 0; nf < 16; ++nf) acc[nf] = (f32x4){0.f, 0.f, 0.f, 0.f};
#pragma unroll
  for (int nf = 0; nf < 16; ++nf) {
    bf16x8 b0 = *reinterpret_cast<const bf16x8*>(wg_f + ((size_t)nf * 64 + lane) * 8);
    bf16x8 b1 = *reinterpret_cast<const bf16x8*>(wg_f + ((size_t)(16 + nf) * 64 + lane) * 8);
    acc[nf] = __builtin_amdgcn_mfma_f32_16x16x32_bf16(a0, b0, acc[nf], 0, 0, 0);
    acc[nf] = __builtin_amdgcn_mfma_f32_16x16x32_bf16(a1, b1, acc[nf], 0, 0, 0);
  }
  char* hb = hlds + wave * 8192;
#pragma unroll
  for (int nf = 0; nf < 16; ++nf)
#pragma unroll
    for (int r = 0; r < 4; ++r) {
      int row = lg * 4 + r;
      float x = acc[nf][r];
      float g = 1.0f / (1.0f + __expf(-x));
      float ov = bf2f(o[(rb + row) * HD + nf * 16 + l15]);
      *reinterpret_cast<short*>(
          hb + row * 512 + (((nf * 16 + l15) * 2) ^ ((row & 7) << 4))) = f2bs(g * ov);
    }
  __syncthreads();
  f32x4 acc3[4];
#pragma unroll
  for (int nf2 = 0; nf2 < 4; ++nf2) acc3[nf2] = (f32x4){0.f, 0.f, 0.f, 0.f};
#pragma unroll
  for (int ks2 = 0; ks2 < 8; ++ks2) {
    bf16x8 a2 = *reinterpret_cast<const bf16x8*>(
        hb + l15 * 512 + ((ks2 * 64 + lg * 16) ^ ((l15 & 7) << 4)));
#pragma unroll
    for (int nf2 = 0; nf2 < 4; ++nf2) {
      bf16x8 b = *reinterpret_cast<const bf16x8*>(
          wpo_f + ((size_t)(ks2 * 4 + nf2) * 64 + lane) * 8);
      acc3[nf2] = __builtin_amdgcn_mfma_f32_16x16x32_bf16(a2, b, acc3[nf2], 0, 0, 0);
    }
  }
#pragma unroll
  for (int nf2 = 0; nf2 < 4; ++nf2)
#pragma unroll
    for (int r = 0; r < 4; ++r) {
      size_t a = (rb + lg * 4 + r) * CM + nf2 * 16 + l15;
      m1out[a] = m0[a] + acc3[nf2][r];
    }
}

// ---------------- transition via MFMA: m2 = m1 + (silu(tn@w1)*(tn@w2))@w3 ---
__global__ __launch_bounds__(256, 1) void k_transition(const float* __restrict__ nw,
                                                       const float* __restrict__ nb,
                                                       const short* __restrict__ w1_f,
                                                       const short* __restrict__ w2_f,
                                                       const short* __restrict__ w3_f,
                                                       float* __restrict__ mio) {
  __shared__ __align__(16) char hlds[32768];
  int t = threadIdx.x, wave = t >> 6, lane = t & 63;
  int lg = lane >> 4, l15 = lane & 15;
  size_t rb = (size_t)blockIdx.x * 64 + wave * 16;
  // in-register LayerNorm: lane handles row rb+l15, k = {ks*32+lg*8 .. +8}
  const float* mrow = mio + (rb + l15) * CM;
  float4 x0 = *reinterpret_cast<const float4*>(mrow + lg * 8);
  float4 x1 = *reinterpret_cast<const float4*>(mrow + lg * 8 + 4);
  float4 x2 = *reinterpret_cast<const float4*>(mrow + 32 + lg * 8);
  float4 x3 = *reinterpret_cast<const float4*>(mrow + 32 + lg * 8 + 4);
  float s = x0.x + x0.y + x0.z + x0.w + x1.x + x1.y + x1.z + x1.w +
            x2.x + x2.y + x2.z + x2.w + x3.x + x3.y + x3.z + x3.w;
  float sq = x0.x * x0.x + x0.y * x0.y + x0.z * x0.z + x0.w * x0.w +
             x1.x * x1.x + x1.y * x1.y + x1.z * x1.z + x1.w * x1.w +
             x2.x * x2.x + x2.y * x2.y + x2.z * x2.z + x2.w * x2.w +
             x3.x * x3.x + x3.y * x3.y + x3.z * x3.z + x3.w * x3.w;
  s += __shfl_xor(s, 16); s += __shfl_xor(s, 32);
  sq += __shfl_xor(sq, 16); sq += __shfl_xor(sq, 32);
  float mu = s * (1.0f / CM);
  float var = sq * (1.0f / CM) - mu * mu;
  float rs = rsqrtf(var + 1e-5f);
  float4 g0 = *reinterpret_cast<const float4*>(nw + lg * 8);
  float4 g1 = *reinterpret_cast<const float4*>(nw + lg * 8 + 4);
  float4 g2 = *reinterpret_cast<const float4*>(nw + 32 + lg * 8);
  float4 g3 = *reinterpret_cast<const float4*>(nw + 32 + lg * 8 + 4);
  float4 c0 = *reinterpret_cast<const float4*>(nb + lg * 8);
  float4 c1 = *reinterpret_cast<const float4*>(nb + lg * 8 + 4);
  float4 c2 = *reinterpret_cast<const float4*>(nb + 32 + lg * 8);
  float4 c3 = *reinterpret_cast<const float4*>(nb + 32 + lg * 8 + 4);
  short av[16];
  av[0] = f2bs((x0.x - mu) * rs * g0.x + c0.x);
  av[1] = f2bs((x0.y - mu) * rs * g0.y + c0.y);
  av[2] = f2bs((x0.z - mu) * rs * g0.z + c0.z);
  av[3] = f2bs((x0.w - mu) * rs * g0.w + c0.w);
  av[4] = f2bs((x1.x - mu) * rs * g1.x + c1.x);
  av[5] = f2bs((x1.y - mu) * rs * g1.y + c1.y);
  av[6] = f2bs((x1.z - mu) * rs * g1.z + c1.z);
  av[7] = f2bs((x1.w - mu) * rs * g1.w + c1.w);
  av[8] = f2bs((x2.x - mu) * rs * g2.x + c2.x);
  av[9] = f2bs((x2.y - mu) * rs * g2.y + c2.y);
  av[10] = f2bs((x2.z - mu) * rs * g2.z + c2.z);
  av[11] = f2bs((x2.w - mu) * rs * g2.w + c2.w);
  av[12] = f2bs((x3.x - mu) * rs * g3.x + c3.x);
  av[13] = f2bs((x3.y - mu) * rs * g3.y + c3.y);
  av[14] = f2bs((x3.z - mu) * rs * g3.z + c3.z);
  av[15] = f2bs((x3.w - mu) * rs * g3.w + c3.w);
  bf16x8 a0 = *reinterpret_cast<const bf16x8*>(&av[0]);
  bf16x8 a1 = *reinterpret_cast<const bf16x8*>(&av[8]);
  f32x4 acc1[16], acc2[16];
#pragma unroll
  for (int nf = 0; nf < 16; ++nf) {
    acc1[nf] = (f32x4){0.f, 0.f, 0.f, 0.f};
    acc2[nf] = (f32x4){0.f, 0.f, 0.f, 0.f};
  }
#pragma unroll
  for (int nf = 0; nf < 16; ++nf) {
    bf16x8 b10 = *reinterpret_cast<const bf16x8*>(w1_f + ((size_t)nf * 64 + lane) * 8);
    bf16x8 b11 = *reinterpret_cast<const bf16x8*>(w1_f + ((size_t)(16 + nf) * 64 + lane) * 8);
    acc1[nf] = __builtin_amdgcn_mfma_f32_16x16x32_bf16(a0, b10, acc1[nf], 0, 0, 0);
    acc1[nf] = __builtin_amdgcn_mfma_f32_16x16x32_bf16(a1, b11, acc1[nf], 0, 0, 0);
    bf16x8 b20 = *reinterpret_cast<const bf16x8*>(w2_f + ((size_t)nf * 64 + lane) * 8);
    bf16x8 b21 = *reinterpret_cast<const bf16x8*>(w2_f + ((size_t)(16 + nf) * 64 + lane) * 8);
    acc2[nf] = __builtin_amdgcn_mfma_f32_16x16x32_bf16(a0, b20, acc2[nf], 0, 0, 0);
    acc2[nf] = __builtin_amdgcn_mfma_f32_16x16x32_bf16(a1, b21, acc2[nf], 0, 0, 0);
  }
  char* hb = hlds + wave * 8192;
#pragma unroll
  for (int nf = 0; nf < 16; ++nf)
#pragma unroll
    for (int r = 0; r < 4; ++r) {
      int row = lg * 4 + r;
      float x = acc1[nf][r];
      float h = (x / (1.0f + __expf(-x))) * acc2[nf][r];
      *reinterpret_cast<short*>(
          hb + row * 512 + (((nf * 16 + l15) * 2) ^ ((row & 7) << 4))) = f2bs(h);
    }
  __syncthreads();
  f32x4 acc3[4];
#pragma unroll
  for (int nf2 = 0; nf2 < 4; ++nf2) acc3[nf2] = (f32x4){0.f, 0.f, 0.f, 0.f};
#pragma unroll
  for (int ks2 = 0; ks2 < 8; ++ks2) {
    bf16x8 a2 = *reinterpret_cast<const bf16x8*>(
        hb + l15 * 512 + ((ks2 * 64 + lg * 16) ^ ((l15 & 7) << 4)));
#pragma unroll
    for (int nf2 = 0; nf2 < 4; ++nf2) {
      bf16x8 b = *reinterpret_cast<const bf16x8*>(
          w3_f + ((size_t)(ks2 * 4 + nf2) * 64 + lane) * 8);
      acc3[nf2] = __builtin_amdgcn_mfma_f32_16x16x32_bf16(a2, b, acc3[nf2], 0, 0, 0);
    }
  }
#pragma unroll
  for (int nf2 = 0; nf2 < 4; ++nf2)
#pragma unroll
    for (int r = 0; r < 4; ++r) {
      size_t a = (rb + lg * 4 + r) * CM + nf2 * 16 + l15;
      mio[a] = mio[a] + acc3[nf2][r];
    }
}

// ---------------- opm a/b: LN(m2)@wa/wb -> bf16 [m][k], pre-swizzled --------
__global__ __launch_bounds__(256) void k_opm_ab(const float* __restrict__ m2,
                                                const float* __restrict__ nw,
                                                const float* __restrict__ nb,
                                                const float* __restrict__ wa,
                                                const float* __restrict__ wb,
                                                short* __restrict__ at_t,
                                                short* __restrict__ bt_t) {
  int bix = blockIdx.x;
  int sg = bix / N_DIM;
  int i = bix - sg * N_DIM;
  __shared__ float on[64][65];
  __shared__ float wl[2][64][36];
  __shared__ float tl[2][32][65];
  int t = threadIdx.x, w = t >> 6, lane = t & 63;
  float gw = nw[lane], gb = nb[lane];
  for (int rr = 0; rr < 16; ++rr) {
    int sl = w * 16 + rr;
    float x = m2[((size_t)(sg * 64 + sl) * N_DIM + i) * CM + lane];
    float s = x, sq = x * x;
#pragma unroll
    for (int off = 32; off; off >>= 1) {
      s += __shfl_xor(s, off);
      sq += __shfl_xor(sq, off);
    }
    float mu = s * (1.0f / CM);
    float var = sq * (1.0f / CM) - mu * mu;
    float rs = rsqrtf(var + 1e-5f);
    on[sl][lane] = (x - mu) * rs * gw + gb;
  }
  for (int idx = t; idx < 2048; idx += 256) {
    int k = idx >> 5, c = idx & 31;
    wl[0][k][c] = wa[idx];
    wl[1][k][c] = wb[idx];
  }
  __syncthreads();
  int s = t >> 2, c0 = (t & 3) * 8;
  float accA[8], accB[8];
#pragma unroll
  for (int j = 0; j < 8; ++j) { accA[j] = 0.0f; accB[j] = 0.0f; }
  for (int k = 0; k < 64; ++k) {
    float ov = on[s][k];
#pragma unroll
    for (int j = 0; j < 8; ++j) {
      accA[j] += ov * wl[0][k][c0 + j];
      accB[j] += ov * wl[1][k][c0 + j];
    }
  }
#pragma unroll
  for (int j = 0; j < 8; ++j) {
    tl[0][c0 + j][s] = accA[j];
    tl[1][c0 + j][s] = accB[j];
  }
  __syncthreads();
  size_t obase = (size_t)i * 32 * 512 + (size_t)sg * 64;
  for (int idx = t; idx < 2048; idx += 256) {
    int c = idx >> 6, s2 = idx & 63;
    int col = s2 ^ ((c & 7) << 3);
    at_t[obase + (size_t)c * 512 + col] = f2bs(tl[0][c][s2]);
    bt_t[obase + (size_t)c * 512 + col] = f2bs(tl[1][c][s2]);
  }
}

// ---------------- wo_f: fragment-packed wo (bf16) for k_opm -----------------
__global__ __launch_bounds__(256) void k_wot(const float* __restrict__ wo,
                                             short* __restrict__ wo_f) {
  int tg = blockIdx.x * 256 + threadIdx.x;
  int frag = tg >> 6, lane = tg & 63;
  int eblk = frag >> 5, kc = frag & 31;
  int e = eblk * 16 + (lane & 15);
  int kbase = kc * 32 + (lane >> 4) * 8;
  short out[8];
#pragma unroll
  for (int j = 0; j < 8; ++j) out[j] = f2bs(wo[(size_t)(kbase + j) * CZ + e]);
  *reinterpret_cast<float4*>(&wo_f[(size_t)tg * 8]) =
      *reinterpret_cast<const float4*>(out);
}

// ---------------- OPM via MFMA: 256x256 op tile (K=512) + fused projection --
__global__ __launch_bounds__(512, 2) void k_opm(const short* __restrict__ at_t,
                                                const short* __restrict__ bt_t,
                                                const short* __restrict__ wo_f,
                                                const float* __restrict__ bo,
                                                const float* __restrict__ z0,
                                                float* __restrict__ z1) {
  int g = blockIdx.x;
  int xcd = g & 7, u = g >> 3;
  int bm = xcd * 6 + (u % 6), bn = u / 6;
  __shared__ __align__(16) char lds8[65536];
  int t = threadIdx.x, wave = t >> 6, lane = t & 63;
  int wm = wave >> 2, wn = wave & 3;
  int lg = lane >> 4, l15 = lane & 15;
  f32x4 acc[8][4];
#pragma unroll
  for (int a = 0; a < 8; ++a)
#pragma unroll
    for (int b = 0; b < 4; ++b) acc[a][b] = (f32x4){0.f, 0.f, 0.f, 0.f};
  const short* A = at_t + (size_t)bm * 256 * 512;
  const short* B = bt_t + (size_t)bn * 256 * 512;
  short* ldsA = (short*)lds8;
  short* ldsB = (short*)(lds8 + 32768);

  for (int k0 = 0; k0 < 512; k0 += 64) {
#pragma unroll
    for (int q = 0; q < 4; ++q) {
      int chunk = wave * 4 + q;
      int ml = chunk * 8 + (lane >> 3);
      size_t goff = (size_t)ml * 512 + k0 + (lane & 7) * 8;
      gl_lds16(A + goff, ldsA + chunk * 512);
      gl_lds16(B + goff, ldsB + chunk * 512);
    }
    __syncthreads();
#pragma unroll
    for (int ks = 0; ks < 2; ++ks) {
      int kk2 = (ks * 32 + lg * 8) * 2;
      bf16x8 bfr[4];
#pragma unroll
      for (int fn = 0; fn < 4; ++fn) {
        int nl = wn * 64 + fn * 16 + l15;
        bfr[fn] = *reinterpret_cast<const bf16x8*>(
            lds8 + 32768 + nl * 128 + (kk2 ^ ((nl & 7) << 4)));
      }
#pragma unroll
      for (int fm = 0; fm < 8; ++fm) {
        int ml = wm * 128 + fm * 16 + l15;
        bf16x8 af = *reinterpret_cast<const bf16x8*>(
            lds8 + ml * 128 + (kk2 ^ ((ml & 7) << 4)));
#pragma unroll
        for (int fn = 0; fn < 4; ++fn)
          acc[fm][fn] = __builtin_amdgcn_mfma_f32_16x16x32_bf16(
              af, bfr[fn], acc[fm][fn], 0, 0, 0);
      }
    }
    __syncthreads();
  }

  short* P = (short*)lds8;
  const float inv_s = 1.0f / 512.0f;
#pragma unroll
  for (int q = 0; q < 4; ++q) {
    if (wm == (q >> 1)) {
      int fmb = (q & 1) * 4;
#pragma unroll
      for (int fm2 = 0; fm2 < 4; ++fm2) {
        int fm = fmb + fm2;
#pragma unroll
        for (int fn = 0; fn < 4; ++fn)
#pragma unroll
          for (int r = 0; r < 4; ++r) {
            int m = wm * 128 + fm * 16 + lg * 4 + r;
            int n = wn * 64 + fn * 16 + l15;
            int prow = ((m >> 5) & 1) * 8 + (n >> 5);
            int cd = ((m & 31) << 5) | (n & 31);
            P[prow * 1032 + cd] = f2bs(acc[fm][fn][r] * inv_s);
          }
      }
    }
    __syncthreads();
    f32x4 pacc = (f32x4){0.f, 0.f, 0.f, 0.f};
    int e = wave * 16 + l15;
    for (int c0 = 0; c0 < 1024; c0 += 32) {
      bf16x8 pa = *reinterpret_cast<const bf16x8*>(P + l15 * 1032 + c0 + lg * 8);
      bf16x8 pb = *reinterpret_cast<const bf16x8*>(
          wo_f + ((size_t)(wave * 32 + (c0 >> 5)) * 64 + lane) * 8);
      pacc = __builtin_amdgcn_mfma_f32_16x16x32_bf16(pa, pb, pacc, 0, 0, 0);
    }
    float bov = bo[e];
#pragma unroll
    for (int r = 0; r < 4; ++r) {
      int pair = q * 16 + lg * 4 + r;
      int gi = bm * 8 + (pair >> 3), gj = bn * 8 + (pair & 7);
      size_t addr = ((size_t)gi * N_DIM + gj) * CZ + e;
      z1[addr] = z0[addr] + pacc[r] + bov;
    }
    __syncthreads();
  }
}

// ---------------------------------------------------------------------------
extern "C" void kernel_launch(void* const* d_in, const int* in_sizes, int n_in,
                              void* d_out, int out_size, void* d_ws, size_t ws_size,
                              hipStream_t stream) {
  const float* m0 = (const float*)d_in[0];
  const float* z0 = (const float*)d_in[1];
  const float* pwa_nm_w = (const float*)d_in[2];
  const float* pwa_nm_b = (const float*)d_in[3];
  const float* pwa_nz_w = (const float*)d_in[4];
  const float* pwa_nz_b = (const float*)d_in[5];
  const float* pwa_wm = (const float*)d_in[6];
  const float* pwa_wg = (const float*)d_in[7];
  const float* pwa_wz = (const float*)d_in[8];
  const float* pwa_wo = (const float*)d_in[9];
  const float* tr_nw = (const float*)d_in[10];
  const float* tr_nb = (const float*)d_in[11];
  const float* tr_w1 = (const float*)d_in[12];
  const float* tr_w2 = (const float*)d_in[13];
  const float* tr_w3 = (const float*)d_in[14];
  const float* opm_nw = (const float*)d_in[15];
  const float* opm_nb = (const float*)d_in[16];
  const float* opm_wa = (const float*)d_in[17];
  const float* opm_wb = (const float*)d_in[18];
  const float* opm_wo = (const float*)d_in[19];
  const float* opm_bo = (const float*)d_in[20];

  char* ws = (char*)d_ws;
  bf16* mn = (bf16*)(ws);                        // 25,165,824 B
  float* wbuf = (float*)(ws + 25165824);         //  4,718,592 B
  short* vT = (short*)(ws + 29884416);           // 100,663,296 B
  bf16* o = (bf16*)(ws + 130547712);             // 100,663,296 B
  // reuse dead vT region after k_ogemm:
  short* at_t = (short*)(ws + 29884416);         // 12,582,912 B
  short* bt_t = (short*)(ws + 42467328);         // 12,582,912 B
  short* wo_f = (short*)(ws + 55050240);         //    262,144 B

  float* m_out = (float*)d_out;
  float* z1 = m_out + (size_t)S_DIM * N_DIM * CM;
  // packed m-path weights live at the head of the z1 region of d_out
  // (dead scratch until k_opm fully overwrites z1 at the end)
  short* packW = (short*)z1;                     // 6 x 32 KB
  short* wm_f = packW;
  short* wg_f = packW + 16384;
  short* w1_f = packW + 32768;
  short* w2_f = packW + 49152;
  short* wpo_f = packW + 65536;
  short* w3_f = packW + 81920;

  k_wprep<<<48, 256, 0, stream>>>(pwa_wm, pwa_wg, tr_w1, tr_w2, pwa_wo, tr_w3, packW);
  k_ln_m<<<49152, 256, 0, stream>>>(m0, pwa_nm_w, pwa_nm_b, mn);
  k_zb<<<36864, 256, 0, stream>>>(z0, pwa_nz_w, pwa_nz_b, pwa_wz, wbuf);
  k_softmax<<<3072, 128, 0, stream>>>(wbuf);
  k_vgemm<<<3072, 256, 0, stream>>>(mn, wm_f, vT);
  k_ogemm<<<dim3(192, 8), 256, 0, stream>>>(wbuf, vT, o);
  k_pwa_out<<<3072, 256, 0, stream>>>(mn, o, m0, wg_f, wpo_f, m_out);
  k_wot<<<64, 256, 0, stream>>>(opm_wo, wo_f);
  k_transition<<<3072, 256, 0, stream>>>(tr_nw, tr_nb, w1_f, w2_f, w3_f, m_out);
  k_opm_ab<<<3072, 256, 0, stream>>>(m_out, opm_nw, opm_nb, opm_wa, opm_wb, at_t, bt_t);
  k_opm<<<2304, 512, 0, stream>>>(at_t, bt_t, wo_f, opm_bo, z0, z1);
}

// Round 5
// 1078.654 us; speedup vs baseline: 4.6741x; 1.0136x over previous
//
#include <hip/hip_runtime.h>
#include <hip/hip_bf16.h>

#define S_DIM 512
#define N_DIM 384
#define CM 64
#define CZ 128
#define HEADS 8
#define DH 32
#define HD 256

typedef __hip_bfloat16 bf16;
typedef long long i64;
typedef __attribute__((ext_vector_type(8))) short bf16x8;
typedef __attribute__((ext_vector_type(4))) float f32x4;

__device__ __forceinline__ float bf2f(bf16 x) { return __bfloat162float(x); }
__device__ __forceinline__ bf16 f2bf(float x) { return __float2bfloat16(x); }
__device__ __forceinline__ short f2bs(float x) {
  bf16 h = __float2bfloat16(x);
  return *reinterpret_cast<short*>(&h);
}

typedef __attribute__((address_space(3))) unsigned int lds_u32;
typedef __attribute__((address_space(1))) const unsigned int gbl_u32;
__device__ __forceinline__ void gl_lds16(const void* g, void* l) {
  __builtin_amdgcn_global_load_lds((gbl_u32*)g, (lds_u32*)l, 16, 0, 0);
}

// ---------------- weight prep: pack [K][N] fp32 -> bf16 MFMA B-fragments ----
__global__ __launch_bounds__(256) void k_wprep(const float* __restrict__ wm,
                                               const float* __restrict__ wg,
                                               const float* __restrict__ w1,
                                               const float* __restrict__ w2,
                                               const float* __restrict__ wpo,
                                               const float* __restrict__ w3,
                                               short* __restrict__ dst) {
  int widx = blockIdx.x >> 3;
  const float* src;
  int N;
  if (widx == 0) { src = wm; N = 256; }
  else if (widx == 1) { src = wg; N = 256; }
  else if (widx == 2) { src = w1; N = 256; }
  else if (widx == 3) { src = w2; N = 256; }
  else if (widx == 4) { src = wpo; N = 64; }
  else { src = w3; N = 64; }
  int NF = N >> 4;
  int tg = ((blockIdx.x & 7) << 8) | threadIdx.x;
  int frag = tg >> 6, lane = tg & 63, lg = lane >> 4, l15 = lane & 15;
  int ks = frag / NF, nf = frag - ks * NF;
  short out[8];
#pragma unroll
  for (int j = 0; j < 8; ++j)
    out[j] = f2bs(src[(size_t)(ks * 32 + lg * 8 + j) * N + nf * 16 + l15]);
  *reinterpret_cast<float4*>(&dst[((size_t)widx << 14) + ((size_t)tg << 3)]) =
      *reinterpret_cast<const float4*>(out);
}

// ---------------- LayerNorm of m0 -> mn (bf16) ------------------------------
__global__ __launch_bounds__(256) void k_ln_m(const float* __restrict__ m,
                                              const float* __restrict__ w,
                                              const float* __restrict__ b,
                                              bf16* __restrict__ mn) {
  int row = blockIdx.x * 4 + (threadIdx.x >> 6);
  int lane = threadIdx.x & 63;
  float x = m[(size_t)row * CM + lane];
  float s = x, sq = x * x;
#pragma unroll
  for (int off = 32; off; off >>= 1) {
    s += __shfl_xor(s, off);
    sq += __shfl_xor(sq, off);
  }
  float mu = s * (1.0f / CM);
  float var = sq * (1.0f / CM) - mu * mu;
  float rs = rsqrtf(var + 1e-5f);
  mn[(size_t)row * CM + lane] = f2bf((x - mu) * rs * w[lane] + b[lane]);
}

// ---------------- LN(z) + pair-bias logits ---------------------------------
__global__ __launch_bounds__(256) void k_zb(const float* __restrict__ z,
                                            const float* __restrict__ w,
                                            const float* __restrict__ b,
                                            const float* __restrict__ wz,
                                            float* __restrict__ logits) {
  int row = blockIdx.x * 4 + (threadIdx.x >> 6);  // row = i*384 + j
  int lane = threadIdx.x & 63;
  const float* x = z + (size_t)row * CZ;
  float v0 = x[lane], v1 = x[lane + 64];
  float s = v0 + v1, sq = v0 * v0 + v1 * v1;
#pragma unroll
  for (int off = 32; off; off >>= 1) {
    s += __shfl_xor(s, off);
    sq += __shfl_xor(sq, off);
  }
  float mu = s * (1.0f / CZ);
  float var = sq * (1.0f / CZ) - mu * mu;
  float rs = rsqrtf(var + 1e-5f);
  float zn0 = (v0 - mu) * rs * w[lane] + b[lane];
  float zn1 = (v1 - mu) * rs * w[lane + 64] + b[lane + 64];
  int i = row / N_DIM, j = row - i * N_DIM;
  for (int h = 0; h < HEADS; ++h) {
    float p = zn0 * wz[lane * HEADS + h] + zn1 * wz[(lane + 64) * HEADS + h];
#pragma unroll
    for (int off = 32; off; off >>= 1) p += __shfl_xor(p, off);
    if (lane == 0) logits[((size_t)i * HEADS + h) * N_DIM + j] = p;
  }
}

// ---------------- softmax over j (rows of 384), in place --------------------
__global__ __launch_bounds__(128) void k_softmax(float* __restrict__ wb) {
  float* p = wb + (size_t)blockIdx.x * N_DIM;
  int t = threadIdx.x;
  float a0 = p[t], a1 = p[t + 128], a2 = p[t + 256];
  float mx = fmaxf(a0, fmaxf(a1, a2));
  __shared__ float red[2], red2[2];
#pragma unroll
  for (int off = 32; off; off >>= 1) mx = fmaxf(mx, __shfl_xor(mx, off));
  if ((t & 63) == 0) red[t >> 6] = mx;
  __syncthreads();
  mx = fmaxf(red[0], red[1]);
  float e0 = __expf(a0 - mx), e1 = __expf(a1 - mx), e2 = __expf(a2 - mx);
  float s = e0 + e1 + e2;
#pragma unroll
  for (int off = 32; off; off >>= 1) s += __shfl_xor(s, off);
  if ((t & 63) == 0) red2[t >> 6] = s;
  __syncthreads();
  float inv = 1.0f / (red2[0] + red2[1]);
  p[t] = e0 * inv;
  p[t + 128] = e1 * inv;
  p[t + 256] = e2 * inv;
}

// ---------------- wsm fp32 [i][h][j] -> w8 bf16 [h][i][j] -------------------
__global__ __launch_bounds__(256) void k_wsm8(const float* __restrict__ wsm,
                                              short* __restrict__ w8) {
  size_t off = ((size_t)blockIdx.x * 256 + threadIdx.x) * 8;
  int i = (int)(off / 3072);
  int rem = (int)(off - (size_t)i * 3072);
  int h = rem / N_DIM, j = rem - h * N_DIM;
  float4 f0 = *reinterpret_cast<const float4*>(wsm + off);
  float4 f1 = *reinterpret_cast<const float4*>(wsm + off + 4);
  short out[8];
  out[0] = f2bs(f0.x); out[1] = f2bs(f0.y); out[2] = f2bs(f0.z); out[3] = f2bs(f0.w);
  out[4] = f2bs(f1.x); out[5] = f2bs(f1.y); out[6] = f2bs(f1.z); out[7] = f2bs(f1.w);
  *reinterpret_cast<float4*>(&w8[((size_t)h * N_DIM + i) * N_DIM + j]) =
      *reinterpret_cast<const float4*>(out);
}

// ---------------- v = mn @ wm via MFMA, emit vT[h][n][j] (plain) ------------
__global__ __launch_bounds__(256, 1) void k_vgemm(const bf16* __restrict__ mn,
                                                  const short* __restrict__ wm_f,
                                                  short* __restrict__ vT) {
  int blk = blockIdx.x;
  int sblk = blk / 6, j0 = (blk % 6) * 64;
  __shared__ short vt[256 * 64];
  int t = threadIdx.x, wave = t >> 6, lane = t & 63;
  int lg = lane >> 4, l15 = lane & 15;
  size_t rb = (size_t)sblk * N_DIM + j0;
  int rw0 = wave * 16;
  const short* mrow = (const short*)mn + (rb + rw0 + l15) * CM;
  bf16x8 a0 = *reinterpret_cast<const bf16x8*>(mrow + lg * 8);
  bf16x8 a1 = *reinterpret_cast<const bf16x8*>(mrow + 32 + lg * 8);
  f32x4 acc[16];
#pragma unroll
  for (int nf = 0; nf < 16; ++nf) acc[nf] = (f32x4){0.f, 0.f, 0.f, 0.f};
#pragma unroll
  for (int nf = 0; nf < 16; ++nf) {
    bf16x8 b0 = *reinterpret_cast<const bf16x8*>(wm_f + ((size_t)nf * 64 + lane) * 8);
    bf16x8 b1 = *reinterpret_cast<const bf16x8*>(wm_f + ((size_t)(16 + nf) * 64 + lane) * 8);
    acc[nf] = __builtin_amdgcn_mfma_f32_16x16x32_bf16(a0, b0, acc[nf], 0, 0, 0);
    acc[nf] = __builtin_amdgcn_mfma_f32_16x16x32_bf16(a1, b1, acc[nf], 0, 0, 0);
  }
#pragma unroll
  for (int nf = 0; nf < 16; ++nf)
#pragma unroll
    for (int r = 0; r < 4; ++r) {
      int jl = rw0 + lg * 4 + r;
      int hd = nf * 16 + l15;
      vt[hd * 64 + jl] = f2bs(acc[nf][r]);
    }
  __syncthreads();
  int h = t >> 5, d = t & 31;
  size_t gbase = ((size_t)h * 16384 + (size_t)sblk * 32 + d) * 384 + j0;
#pragma unroll
  for (int q = 0; q < 8; ++q)
    *reinterpret_cast<float4*>(&vT[gbase + q * 8]) =
        *reinterpret_cast<const float4*>(&vt[t * 64 + q * 8]);
}

// ---------------- o = W @ V per head, MFMA, dbuf prefetch (BJ=32) -----------
__global__ __launch_bounds__(256, 2) void k_ogemm(const short* __restrict__ w8,
                                                  const short* __restrict__ vT,
                                                  bf16* __restrict__ o) {
  int h = blockIdx.y;
  int u = blockIdx.x;
  int gid = (u & 7) * 24 + (u >> 3);   // bijective XCD chunking (192 = 8*24)
  int nb = gid / 3, ib = gid % 3;
  int i0 = ib * 128;
  __shared__ __align__(16) char lds8[49152];  // W: 2x8KB @0, V: 2x16KB @16384
  char* LW = lds8;
  char* LV = lds8 + 16384;
  int t = threadIdx.x, wave = t >> 6, lane = t & 63;
  int lg = lane >> 4, l15 = lane & 15;
  f32x4 acc[8][4];
#pragma unroll
  for (int a = 0; a < 8; ++a)
#pragma unroll
    for (int b = 0; b < 4; ++b) acc[a][b] = (f32x4){0.f, 0.f, 0.f, 0.f};
  const short* Wb = w8 + ((size_t)h * N_DIM + i0) * N_DIM;
  const short* Vb = vT + ((size_t)h * 16384 + (size_t)nb * 256) * N_DIM;

  auto STAGE = [&](int buf, int kt) {
    int j0 = kt * 32;
#pragma unroll
    for (int q = 0; q < 2; ++q) {
      int c = t + q * 256;
      int ri = c >> 2, s = c & 3;
      gl_lds16(Wb + (size_t)ri * N_DIM + j0 + ((s ^ (ri & 3)) << 3),
               LW + buf * 8192 + c * 16);
    }
#pragma unroll
    for (int q = 0; q < 4; ++q) {
      int c = t + q * 256;
      int rn = c >> 2, s = c & 3;
      gl_lds16(Vb + (size_t)rn * N_DIM + j0 + ((s ^ (rn & 3)) << 3),
               LV + buf * 16384 + c * 16);
    }
  };

  STAGE(0, 0);
  __syncthreads();
  for (int kt = 0; kt < 12; ++kt) {
    int cur = kt & 1;
    if (kt < 11) STAGE(cur ^ 1, kt + 1);
    bf16x8 bfr[4];
#pragma unroll
    for (int fn = 0; fn < 4; ++fn) {
      int nl = wave * 64 + fn * 16 + l15;
      bfr[fn] = *reinterpret_cast<const bf16x8*>(
          LV + cur * 16384 + nl * 64 + ((lg * 16) ^ ((nl & 3) << 4)));
    }
#pragma unroll
    for (int fm = 0; fm < 8; ++fm) {
      int il = fm * 16 + l15;
      bf16x8 af = *reinterpret_cast<const bf16x8*>(
          LW + cur * 8192 + il * 64 + ((lg * 16) ^ ((il & 3) << 4)));
#pragma unroll
      for (int fn = 0; fn < 4; ++fn)
        acc[fm][fn] = __builtin_amdgcn_mfma_f32_16x16x32_bf16(
            af, bfr[fn], acc[fm][fn], 0, 0, 0);
    }
    __syncthreads();
  }
#pragma unroll
  for (int fm = 0; fm < 8; ++fm)
#pragma unroll
    for (int fn = 0; fn < 4; ++fn)
#pragma unroll
      for (int r = 0; r < 4; ++r) {
        int i = i0 + fm * 16 + lg * 4 + r;
        int n = nb * 256 + wave * 64 + fn * 16 + l15;
        int s = n >> 5, d = n & 31;
        o[((size_t)s * N_DIM + i) * HD + h * DH + d] = f2bf(acc[fm][fn][r]);
      }
}

// ---------------- pwa out via MFMA: g=sigmoid(mn@wg); m1 = m0 + (o*g)@wo ----
__global__ __launch_bounds__(256, 1) void k_pwa_out(const bf16* __restrict__ mn,
                                                    const bf16* __restrict__ o,
                                                    const float* __restrict__ m0,
                                                    const short* __restrict__ wg_f,
                                                    const short* __restrict__ wpo_f,
                                                    float* __restrict__ m1out) {
  int blk = blockIdx.x;
  int sblk = blk / 6, j0 = (blk % 6) * 64;
  __shared__ __align__(16) char hlds[32768];
  int t = threadIdx.x, wave = t >> 6, lane = t & 63;
  int lg = lane >> 4, l15 = lane & 15;
  size_t rb = (size_t)sblk * N_DIM + j0 + wave * 16;
  const short* mrow = (const short*)mn + (rb + l15) * CM;
  bf16x8 a0 = *reinterpret_cast<const bf16x8*>(mrow + lg * 8);
  bf16x8 a1 = *reinterpret_cast<const bf16x8*>(mrow + 32 + lg * 8);
  f32x4 acc[16];
#pragma unroll
  for (int nf = 0; nf < 16; ++nf) acc[nf] = (f32x4){0.f, 0.f, 0.f, 0.f};
#pragma unroll
  for (int nf = 0; nf < 16; ++nf) {
    bf16x8 b0 = *reinterpret_cast<const bf16x8*>(wg_f + ((size_t)nf * 64 + lane) * 8);
    bf16x8 b1 = *reinterpret_cast<const bf16x8*>(wg_f + ((size_t)(16 + nf) * 64 + lane) * 8);
    acc[nf] = __builtin_amdgcn_mfma_f32_16x16x32_bf16(a0, b0, acc[nf], 0, 0, 0);
    acc[nf] = __builtin_amdgcn_mfma_f32_16x16x32_bf16(a1, b1, acc[nf], 0, 0, 0);
  }
  char* hb = hlds + wave * 8192;
#pragma unroll
  for (int nf = 0; nf < 16; ++nf)
#pragma unroll
    for (int r = 0; r < 4; ++r) {
      int row = lg * 4 + r;
      float x = acc[nf][r];
      float g = 1.0f / (1.0f + __expf(-x));
      float ov = bf2f(o[(rb + row) * HD + nf * 16 + l15]);
      *reinterpret_cast<short*>(
          hb + row * 512 + (((nf * 16 + l15) * 2) ^ ((row & 7) << 4))) = f2bs(g * ov);
    }
  __syncthreads();
  f32x4 acc3[4];
#pragma unroll
  for (int nf2 = 0; nf2 < 4; ++nf2) acc3[nf2] = (f32x4){0.f, 0.f, 0.f, 0.f};
#pragma unroll
  for (int ks2 = 0; ks2 < 8; ++ks2) {
    bf16x8 a2 = *reinterpret_cast<const bf16x8*>(
        hb + l15 * 512 + ((ks2 * 64 + lg * 16) ^ ((l15 & 7) << 4)));
#pragma unroll
    for (int nf2 = 0; nf2 < 4; ++nf2) {
      bf16x8 b = *reinterpret_cast<const bf16x8*>(
          wpo_f + ((size_t)(ks2 * 4 + nf2) * 64 + lane) * 8);
      acc3[nf2] = __builtin_amdgcn_mfma_f32_16x16x32_bf16(a2, b, acc3[nf2], 0, 0, 0);
    }
  }
#pragma unroll
  for (int nf2 = 0; nf2 < 4; ++nf2)
#pragma unroll
    for (int r = 0; r < 4; ++r) {
      size_t a = (rb + lg * 4 + r) * CM + nf2 * 16 + l15;
      m1out[a] = m0[a] + acc3[nf2][r];
    }
}

// ---------------- transition via MFMA: m2 = m1 + (silu(tn@w1)*(tn@w2))@w3 ---
__global__ __launch_bounds__(256, 1) void k_transition(const float* __restrict__ nw,
                                                       const float* __restrict__ nb,
                                                       const short* __restrict__ w1_f,
                                                       const short* __restrict__ w2_f,
                                                       const short* __restrict__ w3_f,
                                                       float* __restrict__ mio) {
  __shared__ __align__(16) char hlds[32768];
  int t = threadIdx.x, wave = t >> 6, lane = t & 63;
  int lg = lane >> 4, l15 = lane & 15;
  size_t rb = (size_t)blockIdx.x * 64 + wave * 16;
  const float* mrow = mio + (rb + l15) * CM;
  float4 x0 = *reinterpret_cast<const float4*>(mrow + lg * 8);
  float4 x1 = *reinterpret_cast<const float4*>(mrow + lg * 8 + 4);
  float4 x2 = *reinterpret_cast<const float4*>(mrow + 32 + lg * 8);
  float4 x3 = *reinterpret_cast<const float4*>(mrow + 32 + lg * 8 + 4);
  float s = x0.x + x0.y + x0.z + x0.w + x1.x + x1.y + x1.z + x1.w +
            x2.x + x2.y + x2.z + x2.w + x3.x + x3.y + x3.z + x3.w;
  float sq = x0.x * x0.x + x0.y * x0.y + x0.z * x0.z + x0.w * x0.w +
             x1.x * x1.x + x1.y * x1.y + x1.z * x1.z + x1.w * x1.w +
             x2.x * x2.x + x2.y * x2.y + x2.z * x2.z + x2.w * x2.w +
             x3.x * x3.x + x3.y * x3.y + x3.z * x3.z + x3.w * x3.w;
  s += __shfl_xor(s, 16); s += __shfl_xor(s, 32);
  sq += __shfl_xor(sq, 16); sq += __shfl_xor(sq, 32);
  float mu = s * (1.0f / CM);
  float var = sq * (1.0f / CM) - mu * mu;
  float rs = rsqrtf(var + 1e-5f);
  float4 g0 = *reinterpret_cast<const float4*>(nw + lg * 8);
  float4 g1 = *reinterpret_cast<const float4*>(nw + lg * 8 + 4);
  float4 g2 = *reinterpret_cast<const float4*>(nw + 32 + lg * 8);
  float4 g3 = *reinterpret_cast<const float4*>(nw + 32 + lg * 8 + 4);
  float4 c0 = *reinterpret_cast<const float4*>(nb + lg * 8);
  float4 c1 = *reinterpret_cast<const float4*>(nb + lg * 8 + 4);
  float4 c2 = *reinterpret_cast<const float4*>(nb + 32 + lg * 8);
  float4 c3 = *reinterpret_cast<const float4*>(nb + 32 + lg * 8 + 4);
  short av[16];
  av[0] = f2bs((x0.x - mu) * rs * g0.x + c0.x);
  av[1] = f2bs((x0.y - mu) * rs * g0.y + c0.y);
  av[2] = f2bs((x0.z - mu) * rs * g0.z + c0.z);
  av[3] = f2bs((x0.w - mu) * rs * g0.w + c0.w);
  av[4] = f2bs((x1.x - mu) * rs * g1.x + c1.x);
  av[5] = f2bs((x1.y - mu) * rs * g1.y + c1.y);
  av[6] = f2bs((x1.z - mu) * rs * g1.z + c1.z);
  av[7] = f2bs((x1.w - mu) * rs * g1.w + c1.w);
  av[8] = f2bs((x2.x - mu) * rs * g2.x + c2.x);
  av[9] = f2bs((x2.y - mu) * rs * g2.y + c2.y);
  av[10] = f2bs((x2.z - mu) * rs * g2.z + c2.z);
  av[11] = f2bs((x2.w - mu) * rs * g2.w + c2.w);
  av[12] = f2bs((x3.x - mu) * rs * g3.x + c3.x);
  av[13] = f2bs((x3.y - mu) * rs * g3.y + c3.y);
  av[14] = f2bs((x3.z - mu) * rs * g3.z + c3.z);
  av[15] = f2bs((x3.w - mu) * rs * g3.w + c3.w);
  bf16x8 a0 = *reinterpret_cast<const bf16x8*>(&av[0]);
  bf16x8 a1 = *reinterpret_cast<const bf16x8*>(&av[8]);
  f32x4 acc1[16], acc2[16];
#pragma unroll
  for (int nf = 0; nf < 16; ++nf) {
    acc1[nf] = (f32x4){0.f, 0.f, 0.f, 0.f};
    acc2[nf] = (f32x4){0.f, 0.f, 0.f, 0.f};
  }
#pragma unroll
  for (int nf = 0; nf < 16; ++nf) {
    bf16x8 b10 = *reinterpret_cast<const bf16x8*>(w1_f + ((size_t)nf * 64 + lane) * 8);
    bf16x8 b11 = *reinterpret_cast<const bf16x8*>(w1_f + ((size_t)(16 + nf) * 64 + lane) * 8);
    acc1[nf] = __builtin_amdgcn_mfma_f32_16x16x32_bf16(a0, b10, acc1[nf], 0, 0, 0);
    acc1[nf] = __builtin_amdgcn_mfma_f32_16x16x32_bf16(a1, b11, acc1[nf], 0, 0, 0);
    bf16x8 b20 = *reinterpret_cast<const bf16x8*>(w2_f + ((size_t)nf * 64 + lane) * 8);
    bf16x8 b21 = *reinterpret_cast<const bf16x8*>(w2_f + ((size_t)(16 + nf) * 64 + lane) * 8);
    acc2[nf] = __builtin_amdgcn_mfma_f32_16x16x32_bf16(a0, b20, acc2[nf], 0, 0, 0);
    acc2[nf] = __builtin_amdgcn_mfma_f32_16x16x32_bf16(a1, b21, acc2[nf], 0, 0, 0);
  }
  char* hb = hlds + wave * 8192;
#pragma unroll
  for (int nf = 0; nf < 16; ++nf)
#pragma unroll
    for (int r = 0; r < 4; ++r) {
      int row = lg * 4 + r;
      float x = acc1[nf][r];
      float h = (x / (1.0f + __expf(-x))) * acc2[nf][r];
      *reinterpret_cast<short*>(
          hb + row * 512 + (((nf * 16 + l15) * 2) ^ ((row & 7) << 4))) = f2bs(h);
    }
  __syncthreads();
  f32x4 acc3[4];
#pragma unroll
  for (int nf2 = 0; nf2 < 4; ++nf2) acc3[nf2] = (f32x4){0.f, 0.f, 0.f, 0.f};
#pragma unroll
  for (int ks2 = 0; ks2 < 8; ++ks2) {
    bf16x8 a2 = *reinterpret_cast<const bf16x8*>(
        hb + l15 * 512 + ((ks2 * 64 + lg * 16) ^ ((l15 & 7) << 4)));
#pragma unroll
    for (int nf2 = 0; nf2 < 4; ++nf2) {
      bf16x8 b = *reinterpret_cast<const bf16x8*>(
          w3_f + ((size_t)(ks2 * 4 + nf2) * 64 + lane) * 8);
      acc3[nf2] = __builtin_amdgcn_mfma_f32_16x16x32_bf16(a2, b, acc3[nf2], 0, 0, 0);
    }
  }
#pragma unroll
  for (int nf2 = 0; nf2 < 4; ++nf2)
#pragma unroll
    for (int r = 0; r < 4; ++r) {
      size_t a = (rb + lg * 4 + r) * CM + nf2 * 16 + l15;
      mio[a] = mio[a] + acc3[nf2][r];
    }
}

// ---------------- opm a/b: LN(m2)@wa/wb -> fp8 e4m3, plain [m][k] -----------
__global__ __launch_bounds__(256) void k_opm_ab(const float* __restrict__ m2,
                                                const float* __restrict__ nw,
                                                const float* __restrict__ nb,
                                                const float* __restrict__ wa,
                                                const float* __restrict__ wb,
                                                unsigned char* __restrict__ at8,
                                                unsigned char* __restrict__ bt8) {
  int bix = blockIdx.x;
  int sg = bix / N_DIM;
  int i = bix - sg * N_DIM;
  __shared__ float on[64][65];
  __shared__ float wl[2][64][36];
  __shared__ float tl[2][32][65];
  int t = threadIdx.x, w = t >> 6, lane = t & 63;
  float gw = nw[lane], gb = nb[lane];
  for (int rr = 0; rr < 16; ++rr) {
    int sl = w * 16 + rr;
    float x = m2[((size_t)(sg * 64 + sl) * N_DIM + i) * CM + lane];
    float s = x, sq = x * x;
#pragma unroll
    for (int off = 32; off; off >>= 1) {
      s += __shfl_xor(s, off);
      sq += __shfl_xor(sq, off);
    }
    float mu = s * (1.0f / CM);
    float var = sq * (1.0f / CM) - mu * mu;
    float rs = rsqrtf(var + 1e-5f);
    on[sl][lane] = (x - mu) * rs * gw + gb;
  }
  for (int idx = t; idx < 2048; idx += 256) {
    int k = idx >> 5, c = idx & 31;
    wl[0][k][c] = wa[idx];
    wl[1][k][c] = wb[idx];
  }
  __syncthreads();
  int s = t >> 2, c0 = (t & 3) * 8;
  float accA[8], accB[8];
#pragma unroll
  for (int j = 0; j < 8; ++j) { accA[j] = 0.0f; accB[j] = 0.0f; }
  for (int k = 0; k < 64; ++k) {
    float ov = on[s][k];
#pragma unroll
    for (int j = 0; j < 8; ++j) {
      accA[j] += ov * wl[0][k][c0 + j];
      accB[j] += ov * wl[1][k][c0 + j];
    }
  }
#pragma unroll
  for (int j = 0; j < 8; ++j) {
    tl[0][c0 + j][s] = accA[j];
    tl[1][c0 + j][s] = accB[j];
  }
  __syncthreads();
  // fp8 pack: thread -> (c = t>>3, 8 consecutive s)
  int cc = t >> 3, s8 = (t & 7) * 8;
  size_t ob = ((size_t)i * 32 + cc) * 512 + (size_t)sg * 64 + s8;
  unsigned int p0 = 0, p1 = 0;
  p0 = __builtin_amdgcn_cvt_pk_fp8_f32(tl[0][cc][s8 + 0], tl[0][cc][s8 + 1], p0, false);
  p0 = __builtin_amdgcn_cvt_pk_fp8_f32(tl[0][cc][s8 + 2], tl[0][cc][s8 + 3], p0, true);
  p1 = __builtin_amdgcn_cvt_pk_fp8_f32(tl[0][cc][s8 + 4], tl[0][cc][s8 + 5], p1, false);
  p1 = __builtin_amdgcn_cvt_pk_fp8_f32(tl[0][cc][s8 + 6], tl[0][cc][s8 + 7], p1, true);
  uint2 pa = {p0, p1};
  *reinterpret_cast<uint2*>(at8 + ob) = pa;
  p0 = 0; p1 = 0;
  p0 = __builtin_amdgcn_cvt_pk_fp8_f32(tl[1][cc][s8 + 0], tl[1][cc][s8 + 1], p0, false);
  p0 = __builtin_amdgcn_cvt_pk_fp8_f32(tl[1][cc][s8 + 2], tl[1][cc][s8 + 3], p0, true);
  p1 = __builtin_amdgcn_cvt_pk_fp8_f32(tl[1][cc][s8 + 4], tl[1][cc][s8 + 5], p1, false);
  p1 = __builtin_amdgcn_cvt_pk_fp8_f32(tl[1][cc][s8 + 6], tl[1][cc][s8 + 7], p1, true);
  uint2 pb = {p0, p1};
  *reinterpret_cast<uint2*>(bt8 + ob) = pb;
}

// ---------------- wo_f: fragment-packed wo (bf16) for k_opm -----------------
__global__ __launch_bounds__(256) void k_wot(const float* __restrict__ wo,
                                             short* __restrict__ wo_f) {
  int tg = blockIdx.x * 256 + threadIdx.x;
  int frag = tg >> 6, lane = tg & 63;
  int eblk = frag >> 5, kc = frag & 31;
  int e = eblk * 16 + (lane & 15);
  int kbase = kc * 32 + (lane >> 4) * 8;
  short out[8];
#pragma unroll
  for (int j = 0; j < 8; ++j) out[j] = f2bs(wo[(size_t)(kbase + j) * CZ + e]);
  *reinterpret_cast<float4*>(&wo_f[(size_t)tg * 8]) =
      *reinterpret_cast<const float4*>(out);
}

// ---------------- OPM: fp8 MFMA 256x256 op tile, dbuf prefetch, fused proj --
__global__ __launch_bounds__(512, 2) void k_opm(const unsigned char* __restrict__ at8,
                                                const unsigned char* __restrict__ bt8,
                                                const short* __restrict__ wo_f,
                                                const float* __restrict__ bo,
                                                const float* __restrict__ z0,
                                                float* __restrict__ z1) {
  // 2D XCD regions: each XCD owns 12 bm x 24 bn (bijective, 2304 = 8*288)
  int g = blockIdx.x;
  int xcd = g & 7, u = g >> 3;
  int bm = (xcd >> 1) * 12 + (u % 12);
  int bn = (xcd & 1) * 24 + (u / 12);
  __shared__ __align__(16) char lds8[65536];  // A: 2x16KB @0, B: 2x16KB @32768
  char* LA = lds8;
  char* LB = lds8 + 32768;
  int t = threadIdx.x, wave = t >> 6, lane = t & 63;
  int wm = wave >> 2, wn = wave & 3;
  int lg = lane >> 4, l15 = lane & 15;
  f32x4 acc[8][4];
#pragma unroll
  for (int a = 0; a < 8; ++a)
#pragma unroll
    for (int b = 0; b < 4; ++b) acc[a][b] = (f32x4){0.f, 0.f, 0.f, 0.f};
  const unsigned char* A = at8 + (size_t)bm * 131072;
  const unsigned char* B = bt8 + (size_t)bn * 131072;

  auto STAGE = [&](int buf, int kt) {
#pragma unroll
    for (int q = 0; q < 2; ++q) {
      int c = t + q * 512;
      int m = c >> 2, sl = c & 3;
      int so = kt * 64 + ((sl ^ (m & 3)) << 4);
      gl_lds16(A + (size_t)m * 512 + so, LA + buf * 16384 + c * 16);
      gl_lds16(B + (size_t)m * 512 + so, LB + buf * 16384 + c * 16);
    }
  };

  STAGE(0, 0);
  __syncthreads();
  for (int kt = 0; kt < 8; ++kt) {
    int cur = kt & 1;
    if (kt < 7) STAGE(cur ^ 1, kt + 1);
#pragma unroll
    for (int ks = 0; ks < 2; ++ks) {
      int kk = ks * 32 + lg * 8;
      i64 bfr[4];
#pragma unroll
      for (int fn = 0; fn < 4; ++fn) {
        int n = wn * 64 + fn * 16 + l15;
        bfr[fn] = *reinterpret_cast<const i64*>(
            LB + cur * 16384 + n * 64 + (kk ^ ((n & 3) << 4)));
      }
#pragma unroll
      for (int fm = 0; fm < 8; ++fm) {
        int m = wm * 128 + fm * 16 + l15;
        i64 af = *reinterpret_cast<const i64*>(
            LA + cur * 16384 + m * 64 + (kk ^ ((m & 3) << 4)));
#pragma unroll
        for (int fn = 0; fn < 4; ++fn)
          acc[fm][fn] = __builtin_amdgcn_mfma_f32_16x16x32_fp8_fp8(
              af, bfr[fn], acc[fm][fn], 0, 0, 0);
      }
    }
    __syncthreads();
  }

  // P[16][1032] bf16 overlays lds8; col XOR-swizzled by (col>>7)&7
  short* P = (short*)lds8;
  const float inv_s = 1.0f / 512.0f;
#pragma unroll
  for (int q = 0; q < 4; ++q) {
    if (wm == (q >> 1)) {
      int fmb = (q & 1) * 4;
#pragma unroll
      for (int fm2 = 0; fm2 < 4; ++fm2) {
        int fm = fmb + fm2;
#pragma unroll
        for (int fn = 0; fn < 4; ++fn)
#pragma unroll
          for (int r = 0; r < 4; ++r) {
            int m = wm * 128 + fm * 16 + lg * 4 + r;
            int n = wn * 64 + fn * 16 + l15;
            int prow = ((m >> 5) & 1) * 8 + (n >> 5);
            int cd = ((m & 31) << 5) | (n & 31);
            int pc = cd ^ (((cd >> 7) & 7) << 3);
            P[prow * 1032 + pc] = f2bs(acc[fm][fn][r] * inv_s);
          }
      }
    }
    __syncthreads();
    f32x4 pacc = (f32x4){0.f, 0.f, 0.f, 0.f};
    int e = wave * 16 + l15;
    for (int c0 = 0; c0 < 1024; c0 += 32) {
      int col = c0 + lg * 8;
      int pc = col ^ (((col >> 7) & 7) << 3);
      bf16x8 pa = *reinterpret_cast<const bf16x8*>(P + l15 * 1032 + pc);
      bf16x8 pb = *reinterpret_cast<const bf16x8*>(
          wo_f + ((size_t)(wave * 32 + (c0 >> 5)) * 64 + lane) * 8);
      pacc = __builtin_amdgcn_mfma_f32_16x16x32_bf16(pa, pb, pacc, 0, 0, 0);
    }
    float bov = bo[e];
#pragma unroll
    for (int r = 0; r < 4; ++r) {
      int pair = q * 16 + lg * 4 + r;
      int gi = bm * 8 + (pair >> 3), gj = bn * 8 + (pair & 7);
      size_t addr = ((size_t)gi * N_DIM + gj) * CZ + e;
      z1[addr] = z0[addr] + pacc[r] + bov;
    }
    __syncthreads();
  }
}

// ---------------------------------------------------------------------------
extern "C" void kernel_launch(void* const* d_in, const int* in_sizes, int n_in,
                              void* d_out, int out_size, void* d_ws, size_t ws_size,
                              hipStream_t stream) {
  const float* m0 = (const float*)d_in[0];
  const float* z0 = (const float*)d_in[1];
  const float* pwa_nm_w = (const float*)d_in[2];
  const float* pwa_nm_b = (const float*)d_in[3];
  const float* pwa_nz_w = (const float*)d_in[4];
  const float* pwa_nz_b = (const float*)d_in[5];
  const float* pwa_wm = (const float*)d_in[6];
  const float* pwa_wg = (const float*)d_in[7];
  const float* pwa_wz = (const float*)d_in[8];
  const float* pwa_wo = (const float*)d_in[9];
  const float* tr_nw = (const float*)d_in[10];
  const float* tr_nb = (const float*)d_in[11];
  const float* tr_w1 = (const float*)d_in[12];
  const float* tr_w2 = (const float*)d_in[13];
  const float* tr_w3 = (const float*)d_in[14];
  const float* opm_nw = (const float*)d_in[15];
  const float* opm_nb = (const float*)d_in[16];
  const float* opm_wa = (const float*)d_in[17];
  const float* opm_wb = (const float*)d_in[18];
  const float* opm_wo = (const float*)d_in[19];
  const float* opm_bo = (const float*)d_in[20];

  char* ws = (char*)d_ws;
  bf16* mn = (bf16*)(ws);                        // 25,165,824 B
  float* wbuf = (float*)(ws + 25165824);         //  4,718,592 B
  short* vT = (short*)(ws + 29884416);           // 100,663,296 B
  bf16* o = (bf16*)(ws + 130547712);             // 100,663,296 B
  // reuse dead vT region after k_ogemm:
  unsigned char* at8 = (unsigned char*)(ws + 29884416);  // 6,291,456 B
  unsigned char* bt8 = at8 + 6291456;                    // 6,291,456 B
  short* wo_f = (short*)(ws + 55050240);                 //   262,144 B

  float* m_out = (float*)d_out;
  float* z1 = m_out + (size_t)S_DIM * N_DIM * CM;
  // scratch in the z1 region of d_out (dead until k_opm overwrites all of z1)
  short* packW = (short*)z1;                     // 6 x 32 KB
  short* wm_f = packW;
  short* wg_f = packW + 16384;
  short* w1_f = packW + 32768;
  short* w2_f = packW + 49152;
  short* wpo_f = packW + 65536;
  short* w3_f = packW + 81920;
  short* w8 = (short*)((char*)z1 + 262144);      // 2,359,296 B (bf16 softmax W)

  k_wprep<<<48, 256, 0, stream>>>(pwa_wm, pwa_wg, tr_w1, tr_w2, pwa_wo, tr_w3, packW);
  k_ln_m<<<49152, 256, 0, stream>>>(m0, pwa_nm_w, pwa_nm_b, mn);
  k_zb<<<36864, 256, 0, stream>>>(z0, pwa_nz_w, pwa_nz_b, pwa_wz, wbuf);
  k_softmax<<<3072, 128, 0, stream>>>(wbuf);
  k_wsm8<<<576, 256, 0, stream>>>(wbuf, w8);
  k_vgemm<<<3072, 256, 0, stream>>>(mn, wm_f, vT);
  k_ogemm<<<dim3(192, 8), 256, 0, stream>>>(w8, vT, o);
  k_pwa_out<<<3072, 256, 0, stream>>>(mn, o, m0, wg_f, wpo_f, m_out);
  k_wot<<<64, 256, 0, stream>>>(opm_wo, wo_f);
  k_transition<<<3072, 256, 0, stream>>>(tr_nw, tr_nb, w1_f, w2_f, w3_f, m_out);
  k_opm_ab<<<3072, 256, 0, stream>>>(m_out, opm_nw, opm_nb, opm_wa, opm_wb, at8, bt8);
  k_opm<<<2304, 512, 0, stream>>>(at8, bt8, wo_f, opm_bo, z0, z1);
}

// Round 6
// 1051.242 us; speedup vs baseline: 4.7959x; 1.0261x over previous
//
#include <hip/hip_runtime.h>
#include <hip/hip_bf16.h>

#define S_DIM 512
#define N_DIM 384
#define CM 64
#define CZ 128
#define HEADS 8
#define DH 32
#define HD 256

typedef __hip_bfloat16 bf16;
typedef long long i64;
typedef __attribute__((ext_vector_type(8))) short bf16x8;
typedef __attribute__((ext_vector_type(4))) float f32x4;

__device__ __forceinline__ float bf2f(bf16 x) { return __bfloat162float(x); }
__device__ __forceinline__ bf16 f2bf(float x) { return __float2bfloat16(x); }
__device__ __forceinline__ short f2bs(float x) {
  bf16 h = __float2bfloat16(x);
  return *reinterpret_cast<short*>(&h);
}

typedef __attribute__((address_space(3))) unsigned int lds_u32;
typedef __attribute__((address_space(1))) const unsigned int gbl_u32;
__device__ __forceinline__ void gl_lds16(const void* g, void* l) {
  __builtin_amdgcn_global_load_lds((gbl_u32*)g, (lds_u32*)l, 16, 0, 0);
}

// ---------------- weight prep: pack [K][N] fp32 -> bf16 MFMA B-fragments ----
__global__ __launch_bounds__(256) void k_wprep(const float* __restrict__ wm,
                                               const float* __restrict__ wg,
                                               const float* __restrict__ w1,
                                               const float* __restrict__ w2,
                                               const float* __restrict__ wpo,
                                               const float* __restrict__ w3,
                                               short* __restrict__ dst) {
  int widx = blockIdx.x >> 3;
  const float* src;
  int N;
  if (widx == 0) { src = wm; N = 256; }
  else if (widx == 1) { src = wg; N = 256; }
  else if (widx == 2) { src = w1; N = 256; }
  else if (widx == 3) { src = w2; N = 256; }
  else if (widx == 4) { src = wpo; N = 64; }
  else { src = w3; N = 64; }
  int NF = N >> 4;
  int tg = ((blockIdx.x & 7) << 8) | threadIdx.x;
  int frag = tg >> 6, lane = tg & 63, lg = lane >> 4, l15 = lane & 15;
  int ks = frag / NF, nf = frag - ks * NF;
  short out[8];
#pragma unroll
  for (int j = 0; j < 8; ++j)
    out[j] = f2bs(src[(size_t)(ks * 32 + lg * 8 + j) * N + nf * 16 + l15]);
  *reinterpret_cast<float4*>(&dst[((size_t)widx << 14) + ((size_t)tg << 3)]) =
      *reinterpret_cast<const float4*>(out);
}

// ---------------- LayerNorm of m0 -> mn (bf16) ------------------------------
__global__ __launch_bounds__(256) void k_ln_m(const float* __restrict__ m,
                                              const float* __restrict__ w,
                                              const float* __restrict__ b,
                                              bf16* __restrict__ mn) {
  int row = blockIdx.x * 4 + (threadIdx.x >> 6);
  int lane = threadIdx.x & 63;
  float x = m[(size_t)row * CM + lane];
  float s = x, sq = x * x;
#pragma unroll
  for (int off = 32; off; off >>= 1) {
    s += __shfl_xor(s, off);
    sq += __shfl_xor(sq, off);
  }
  float mu = s * (1.0f / CM);
  float var = sq * (1.0f / CM) - mu * mu;
  float rs = rsqrtf(var + 1e-5f);
  mn[(size_t)row * CM + lane] = f2bf((x - mu) * rs * w[lane] + b[lane]);
}

// ---------------- LN(z) + pair-bias logits ---------------------------------
__global__ __launch_bounds__(256) void k_zb(const float* __restrict__ z,
                                            const float* __restrict__ w,
                                            const float* __restrict__ b,
                                            const float* __restrict__ wz,
                                            float* __restrict__ logits) {
  int row = blockIdx.x * 4 + (threadIdx.x >> 6);  // row = i*384 + j
  int lane = threadIdx.x & 63;
  const float* x = z + (size_t)row * CZ;
  float v0 = x[lane], v1 = x[lane + 64];
  float s = v0 + v1, sq = v0 * v0 + v1 * v1;
#pragma unroll
  for (int off = 32; off; off >>= 1) {
    s += __shfl_xor(s, off);
    sq += __shfl_xor(sq, off);
  }
  float mu = s * (1.0f / CZ);
  float var = sq * (1.0f / CZ) - mu * mu;
  float rs = rsqrtf(var + 1e-5f);
  float zn0 = (v0 - mu) * rs * w[lane] + b[lane];
  float zn1 = (v1 - mu) * rs * w[lane + 64] + b[lane + 64];
  int i = row / N_DIM, j = row - i * N_DIM;
  for (int h = 0; h < HEADS; ++h) {
    float p = zn0 * wz[lane * HEADS + h] + zn1 * wz[(lane + 64) * HEADS + h];
#pragma unroll
    for (int off = 32; off; off >>= 1) p += __shfl_xor(p, off);
    if (lane == 0) logits[((size_t)i * HEADS + h) * N_DIM + j] = p;
  }
}

// ---------------- softmax over j (rows of 384), in place --------------------
__global__ __launch_bounds__(128) void k_softmax(float* __restrict__ wb) {
  float* p = wb + (size_t)blockIdx.x * N_DIM;
  int t = threadIdx.x;
  float a0 = p[t], a1 = p[t + 128], a2 = p[t + 256];
  float mx = fmaxf(a0, fmaxf(a1, a2));
  __shared__ float red[2], red2[2];
#pragma unroll
  for (int off = 32; off; off >>= 1) mx = fmaxf(mx, __shfl_xor(mx, off));
  if ((t & 63) == 0) red[t >> 6] = mx;
  __syncthreads();
  mx = fmaxf(red[0], red[1]);
  float e0 = __expf(a0 - mx), e1 = __expf(a1 - mx), e2 = __expf(a2 - mx);
  float s = e0 + e1 + e2;
#pragma unroll
  for (int off = 32; off; off >>= 1) s += __shfl_xor(s, off);
  if ((t & 63) == 0) red2[t >> 6] = s;
  __syncthreads();
  float inv = 1.0f / (red2[0] + red2[1]);
  p[t] = e0 * inv;
  p[t + 128] = e1 * inv;
  p[t + 256] = e2 * inv;
}

// ---------------- wsm fp32 [i][h][j] -> w8 bf16 [h][i][j] -------------------
__global__ __launch_bounds__(256) void k_wsm8(const float* __restrict__ wsm,
                                              short* __restrict__ w8) {
  size_t off = ((size_t)blockIdx.x * 256 + threadIdx.x) * 8;
  int i = (int)(off / 3072);
  int rem = (int)(off - (size_t)i * 3072);
  int h = rem / N_DIM, j = rem - h * N_DIM;
  float4 f0 = *reinterpret_cast<const float4*>(wsm + off);
  float4 f1 = *reinterpret_cast<const float4*>(wsm + off + 4);
  short out[8];
  out[0] = f2bs(f0.x); out[1] = f2bs(f0.y); out[2] = f2bs(f0.z); out[3] = f2bs(f0.w);
  out[4] = f2bs(f1.x); out[5] = f2bs(f1.y); out[6] = f2bs(f1.z); out[7] = f2bs(f1.w);
  *reinterpret_cast<float4*>(&w8[((size_t)h * N_DIM + i) * N_DIM + j]) =
      *reinterpret_cast<const float4*>(out);
}

// ---------------- v = mn @ wm via MFMA, emit vT[h][n][j] (plain) ------------
__global__ __launch_bounds__(256, 1) void k_vgemm(const bf16* __restrict__ mn,
                                                  const short* __restrict__ wm_f,
                                                  short* __restrict__ vT) {
  int blk = blockIdx.x;
  int sblk = blk / 6, j0 = (blk % 6) * 64;
  __shared__ short vt[256 * 64];
  int t = threadIdx.x, wave = t >> 6, lane = t & 63;
  int lg = lane >> 4, l15 = lane & 15;
  size_t rb = (size_t)sblk * N_DIM + j0;
  int rw0 = wave * 16;
  const short* mrow = (const short*)mn + (rb + rw0 + l15) * CM;
  bf16x8 a0 = *reinterpret_cast<const bf16x8*>(mrow + lg * 8);
  bf16x8 a1 = *reinterpret_cast<const bf16x8*>(mrow + 32 + lg * 8);
  f32x4 acc[16];
#pragma unroll
  for (int nf = 0; nf < 16; ++nf) acc[nf] = (f32x4){0.f, 0.f, 0.f, 0.f};
#pragma unroll
  for (int nf = 0; nf < 16; ++nf) {
    bf16x8 b0 = *reinterpret_cast<const bf16x8*>(wm_f + ((size_t)nf * 64 + lane) * 8);
    bf16x8 b1 = *reinterpret_cast<const bf16x8*>(wm_f + ((size_t)(16 + nf) * 64 + lane) * 8);
    acc[nf] = __builtin_amdgcn_mfma_f32_16x16x32_bf16(a0, b0, acc[nf], 0, 0, 0);
    acc[nf] = __builtin_amdgcn_mfma_f32_16x16x32_bf16(a1, b1, acc[nf], 0, 0, 0);
  }
#pragma unroll
  for (int nf = 0; nf < 16; ++nf)
#pragma unroll
    for (int r = 0; r < 4; ++r) {
      int jl = rw0 + lg * 4 + r;
      int hd = nf * 16 + l15;
      vt[hd * 64 + jl] = f2bs(acc[nf][r]);
    }
  __syncthreads();
  int h = t >> 5, d = t & 31;
  size_t gbase = ((size_t)h * 16384 + (size_t)sblk * 32 + d) * 384 + j0;
#pragma unroll
  for (int q = 0; q < 8; ++q)
    *reinterpret_cast<float4*>(&vT[gbase + q * 8]) =
        *reinterpret_cast<const float4*>(&vt[t * 64 + q * 8]);
}

// ---------------- o = W @ V per head, MFMA, dbuf prefetch (BJ=32) -----------
__global__ __launch_bounds__(256, 2) void k_ogemm(const short* __restrict__ w8,
                                                  const short* __restrict__ vT,
                                                  bf16* __restrict__ o) {
  int h = blockIdx.y;
  int u = blockIdx.x;
  int gid = (u & 7) * 24 + (u >> 3);   // bijective XCD chunking (192 = 8*24)
  int nb = gid / 3, ib = gid % 3;
  int i0 = ib * 128;
  __shared__ __align__(16) char lds8[49152];  // W: 2x8KB @0, V: 2x16KB @16384
  char* LW = lds8;
  char* LV = lds8 + 16384;
  int t = threadIdx.x, wave = t >> 6, lane = t & 63;
  int lg = lane >> 4, l15 = lane & 15;
  f32x4 acc[8][4];
#pragma unroll
  for (int a = 0; a < 8; ++a)
#pragma unroll
    for (int b = 0; b < 4; ++b) acc[a][b] = (f32x4){0.f, 0.f, 0.f, 0.f};
  const short* Wb = w8 + ((size_t)h * N_DIM + i0) * N_DIM;
  const short* Vb = vT + ((size_t)h * 16384 + (size_t)nb * 256) * N_DIM;

  auto STAGE = [&](int buf, int kt) {
    int j0 = kt * 32;
#pragma unroll
    for (int q = 0; q < 2; ++q) {
      int c = t + q * 256;
      int ri = c >> 2, s = c & 3;
      gl_lds16(Wb + (size_t)ri * N_DIM + j0 + ((s ^ (ri & 3)) << 3),
               LW + buf * 8192 + c * 16);
    }
#pragma unroll
    for (int q = 0; q < 4; ++q) {
      int c = t + q * 256;
      int rn = c >> 2, s = c & 3;
      gl_lds16(Vb + (size_t)rn * N_DIM + j0 + ((s ^ (rn & 3)) << 3),
               LV + buf * 16384 + c * 16);
    }
  };

  STAGE(0, 0);
  __syncthreads();
  for (int kt = 0; kt < 12; ++kt) {
    int cur = kt & 1;
    if (kt < 11) STAGE(cur ^ 1, kt + 1);
    bf16x8 bfr[4];
#pragma unroll
    for (int fn = 0; fn < 4; ++fn) {
      int nl = wave * 64 + fn * 16 + l15;
      bfr[fn] = *reinterpret_cast<const bf16x8*>(
          LV + cur * 16384 + nl * 64 + ((lg * 16) ^ ((nl & 3) << 4)));
    }
#pragma unroll
    for (int fm = 0; fm < 8; ++fm) {
      int il = fm * 16 + l15;
      bf16x8 af = *reinterpret_cast<const bf16x8*>(
          LW + cur * 8192 + il * 64 + ((lg * 16) ^ ((il & 3) << 4)));
#pragma unroll
      for (int fn = 0; fn < 4; ++fn)
        acc[fm][fn] = __builtin_amdgcn_mfma_f32_16x16x32_bf16(
            af, bfr[fn], acc[fm][fn], 0, 0, 0);
    }
    __syncthreads();
  }
#pragma unroll
  for (int fm = 0; fm < 8; ++fm)
#pragma unroll
    for (int fn = 0; fn < 4; ++fn)
#pragma unroll
      for (int r = 0; r < 4; ++r) {
        int i = i0 + fm * 16 + lg * 4 + r;
        int n = nb * 256 + wave * 64 + fn * 16 + l15;
        int s = n >> 5, d = n & 31;
        o[((size_t)s * N_DIM + i) * HD + h * DH + d] = f2bf(acc[fm][fn][r]);
      }
}

// ---------------- pwa out via MFMA: g=sigmoid(mn@wg); m1 = m0 + (o*g)@wo ----
__global__ __launch_bounds__(256, 1) void k_pwa_out(const bf16* __restrict__ mn,
                                                    const bf16* __restrict__ o,
                                                    const float* __restrict__ m0,
                                                    const short* __restrict__ wg_f,
                                                    const short* __restrict__ wpo_f,
                                                    float* __restrict__ m1out) {
  int blk = blockIdx.x;
  int sblk = blk / 6, j0 = (blk % 6) * 64;
  __shared__ __align__(16) char hlds[32768];
  int t = threadIdx.x, wave = t >> 6, lane = t & 63;
  int lg = lane >> 4, l15 = lane & 15;
  size_t rb = (size_t)sblk * N_DIM + j0 + wave * 16;
  const short* mrow = (const short*)mn + (rb + l15) * CM;
  bf16x8 a0 = *reinterpret_cast<const bf16x8*>(mrow + lg * 8);
  bf16x8 a1 = *reinterpret_cast<const bf16x8*>(mrow + 32 + lg * 8);
  f32x4 acc[16];
#pragma unroll
  for (int nf = 0; nf < 16; ++nf) acc[nf] = (f32x4){0.f, 0.f, 0.f, 0.f};
#pragma unroll
  for (int nf = 0; nf < 16; ++nf) {
    bf16x8 b0 = *reinterpret_cast<const bf16x8*>(wg_f + ((size_t)nf * 64 + lane) * 8);
    bf16x8 b1 = *reinterpret_cast<const bf16x8*>(wg_f + ((size_t)(16 + nf) * 64 + lane) * 8);
    acc[nf] = __builtin_amdgcn_mfma_f32_16x16x32_bf16(a0, b0, acc[nf], 0, 0, 0);
    acc[nf] = __builtin_amdgcn_mfma_f32_16x16x32_bf16(a1, b1, acc[nf], 0, 0, 0);
  }
  char* hb = hlds + wave * 8192;
#pragma unroll
  for (int nf = 0; nf < 16; ++nf)
#pragma unroll
    for (int r = 0; r < 4; ++r) {
      int row = lg * 4 + r;
      float x = acc[nf][r];
      float g = 1.0f / (1.0f + __expf(-x));
      float ov = bf2f(o[(rb + row) * HD + nf * 16 + l15]);
      *reinterpret_cast<short*>(
          hb + row * 512 + (((nf * 16 + l15) * 2) ^ ((row & 7) << 4))) = f2bs(g * ov);
    }
  __syncthreads();
  f32x4 acc3[4];
#pragma unroll
  for (int nf2 = 0; nf2 < 4; ++nf2) acc3[nf2] = (f32x4){0.f, 0.f, 0.f, 0.f};
#pragma unroll
  for (int ks2 = 0; ks2 < 8; ++ks2) {
    bf16x8 a2 = *reinterpret_cast<const bf16x8*>(
        hb + l15 * 512 + ((ks2 * 64 + lg * 16) ^ ((l15 & 7) << 4)));
#pragma unroll
    for (int nf2 = 0; nf2 < 4; ++nf2) {
      bf16x8 b = *reinterpret_cast<const bf16x8*>(
          wpo_f + ((size_t)(ks2 * 4 + nf2) * 64 + lane) * 8);
      acc3[nf2] = __builtin_amdgcn_mfma_f32_16x16x32_bf16(a2, b, acc3[nf2], 0, 0, 0);
    }
  }
#pragma unroll
  for (int nf2 = 0; nf2 < 4; ++nf2)
#pragma unroll
    for (int r = 0; r < 4; ++r) {
      size_t a = (rb + lg * 4 + r) * CM + nf2 * 16 + l15;
      m1out[a] = m0[a] + acc3[nf2][r];
    }
}

// ---------------- transition via MFMA: m2 = m1 + (silu(tn@w1)*(tn@w2))@w3 ---
__global__ __launch_bounds__(256, 1) void k_transition(const float* __restrict__ nw,
                                                       const float* __restrict__ nb,
                                                       const short* __restrict__ w1_f,
                                                       const short* __restrict__ w2_f,
                                                       const short* __restrict__ w3_f,
                                                       float* __restrict__ mio) {
  __shared__ __align__(16) char hlds[32768];
  int t = threadIdx.x, wave = t >> 6, lane = t & 63;
  int lg = lane >> 4, l15 = lane & 15;
  size_t rb = (size_t)blockIdx.x * 64 + wave * 16;
  const float* mrow = mio + (rb + l15) * CM;
  float4 x0 = *reinterpret_cast<const float4*>(mrow + lg * 8);
  float4 x1 = *reinterpret_cast<const float4*>(mrow + lg * 8 + 4);
  float4 x2 = *reinterpret_cast<const float4*>(mrow + 32 + lg * 8);
  float4 x3 = *reinterpret_cast<const float4*>(mrow + 32 + lg * 8 + 4);
  float s = x0.x + x0.y + x0.z + x0.w + x1.x + x1.y + x1.z + x1.w +
            x2.x + x2.y + x2.z + x2.w + x3.x + x3.y + x3.z + x3.w;
  float sq = x0.x * x0.x + x0.y * x0.y + x0.z * x0.z + x0.w * x0.w +
             x1.x * x1.x + x1.y * x1.y + x1.z * x1.z + x1.w * x1.w +
             x2.x * x2.x + x2.y * x2.y + x2.z * x2.z + x2.w * x2.w +
             x3.x * x3.x + x3.y * x3.y + x3.z * x3.z + x3.w * x3.w;
  s += __shfl_xor(s, 16); s += __shfl_xor(s, 32);
  sq += __shfl_xor(sq, 16); sq += __shfl_xor(sq, 32);
  float mu = s * (1.0f / CM);
  float var = sq * (1.0f / CM) - mu * mu;
  float rs = rsqrtf(var + 1e-5f);
  float4 g0 = *reinterpret_cast<const float4*>(nw + lg * 8);
  float4 g1 = *reinterpret_cast<const float4*>(nw + lg * 8 + 4);
  float4 g2 = *reinterpret_cast<const float4*>(nw + 32 + lg * 8);
  float4 g3 = *reinterpret_cast<const float4*>(nw + 32 + lg * 8 + 4);
  float4 c0 = *reinterpret_cast<const float4*>(nb + lg * 8);
  float4 c1 = *reinterpret_cast<const float4*>(nb + lg * 8 + 4);
  float4 c2 = *reinterpret_cast<const float4*>(nb + 32 + lg * 8);
  float4 c3 = *reinterpret_cast<const float4*>(nb + 32 + lg * 8 + 4);
  short av[16];
  av[0] = f2bs((x0.x - mu) * rs * g0.x + c0.x);
  av[1] = f2bs((x0.y - mu) * rs * g0.y + c0.y);
  av[2] = f2bs((x0.z - mu) * rs * g0.z + c0.z);
  av[3] = f2bs((x0.w - mu) * rs * g0.w + c0.w);
  av[4] = f2bs((x1.x - mu) * rs * g1.x + c1.x);
  av[5] = f2bs((x1.y - mu) * rs * g1.y + c1.y);
  av[6] = f2bs((x1.z - mu) * rs * g1.z + c1.z);
  av[7] = f2bs((x1.w - mu) * rs * g1.w + c1.w);
  av[8] = f2bs((x2.x - mu) * rs * g2.x + c2.x);
  av[9] = f2bs((x2.y - mu) * rs * g2.y + c2.y);
  av[10] = f2bs((x2.z - mu) * rs * g2.z + c2.z);
  av[11] = f2bs((x2.w - mu) * rs * g2.w + c2.w);
  av[12] = f2bs((x3.x - mu) * rs * g3.x + c3.x);
  av[13] = f2bs((x3.y - mu) * rs * g3.y + c3.y);
  av[14] = f2bs((x3.z - mu) * rs * g3.z + c3.z);
  av[15] = f2bs((x3.w - mu) * rs * g3.w + c3.w);
  bf16x8 a0 = *reinterpret_cast<const bf16x8*>(&av[0]);
  bf16x8 a1 = *reinterpret_cast<const bf16x8*>(&av[8]);
  f32x4 acc1[16], acc2[16];
#pragma unroll
  for (int nf = 0; nf < 16; ++nf) {
    acc1[nf] = (f32x4){0.f, 0.f, 0.f, 0.f};
    acc2[nf] = (f32x4){0.f, 0.f, 0.f, 0.f};
  }
#pragma unroll
  for (int nf = 0; nf < 16; ++nf) {
    bf16x8 b10 = *reinterpret_cast<const bf16x8*>(w1_f + ((size_t)nf * 64 + lane) * 8);
    bf16x8 b11 = *reinterpret_cast<const bf16x8*>(w1_f + ((size_t)(16 + nf) * 64 + lane) * 8);
    acc1[nf] = __builtin_amdgcn_mfma_f32_16x16x32_bf16(a0, b10, acc1[nf], 0, 0, 0);
    acc1[nf] = __builtin_amdgcn_mfma_f32_16x16x32_bf16(a1, b11, acc1[nf], 0, 0, 0);
    bf16x8 b20 = *reinterpret_cast<const bf16x8*>(w2_f + ((size_t)nf * 64 + lane) * 8);
    bf16x8 b21 = *reinterpret_cast<const bf16x8*>(w2_f + ((size_t)(16 + nf) * 64 + lane) * 8);
    acc2[nf] = __builtin_amdgcn_mfma_f32_16x16x32_bf16(a0, b20, acc2[nf], 0, 0, 0);
    acc2[nf] = __builtin_amdgcn_mfma_f32_16x16x32_bf16(a1, b21, acc2[nf], 0, 0, 0);
  }
  char* hb = hlds + wave * 8192;
#pragma unroll
  for (int nf = 0; nf < 16; ++nf)
#pragma unroll
    for (int r = 0; r < 4; ++r) {
      int row = lg * 4 + r;
      float x = acc1[nf][r];
      float h = (x / (1.0f + __expf(-x))) * acc2[nf][r];
      *reinterpret_cast<short*>(
          hb + row * 512 + (((nf * 16 + l15) * 2) ^ ((row & 7) << 4))) = f2bs(h);
    }
  __syncthreads();
  f32x4 acc3[4];
#pragma unroll
  for (int nf2 = 0; nf2 < 4; ++nf2) acc3[nf2] = (f32x4){0.f, 0.f, 0.f, 0.f};
#pragma unroll
  for (int ks2 = 0; ks2 < 8; ++ks2) {
    bf16x8 a2 = *reinterpret_cast<const bf16x8*>(
        hb + l15 * 512 + ((ks2 * 64 + lg * 16) ^ ((l15 & 7) << 4)));
#pragma unroll
    for (int nf2 = 0; nf2 < 4; ++nf2) {
      bf16x8 b = *reinterpret_cast<const bf16x8*>(
          w3_f + ((size_t)(ks2 * 4 + nf2) * 64 + lane) * 8);
      acc3[nf2] = __builtin_amdgcn_mfma_f32_16x16x32_bf16(a2, b, acc3[nf2], 0, 0, 0);
    }
  }
#pragma unroll
  for (int nf2 = 0; nf2 < 4; ++nf2)
#pragma unroll
    for (int r = 0; r < 4; ++r) {
      size_t a = (rb + lg * 4 + r) * CM + nf2 * 16 + l15;
      mio[a] = mio[a] + acc3[nf2][r];
    }
}

// ---------------- opm a/b: LN(m2)@wa/wb -> fp8 e4m3, plain [m][k] -----------
__global__ __launch_bounds__(256) void k_opm_ab(const float* __restrict__ m2,
                                                const float* __restrict__ nw,
                                                const float* __restrict__ nb,
                                                const float* __restrict__ wa,
                                                const float* __restrict__ wb,
                                                unsigned char* __restrict__ at8,
                                                unsigned char* __restrict__ bt8) {
  int bix = blockIdx.x;
  int sg = bix / N_DIM;
  int i = bix - sg * N_DIM;
  __shared__ float on[64][65];
  __shared__ float wl[2][64][36];
  __shared__ float tl[2][32][65];
  int t = threadIdx.x, w = t >> 6, lane = t & 63;
  float gw = nw[lane], gb = nb[lane];
  for (int rr = 0; rr < 16; ++rr) {
    int sl = w * 16 + rr;
    float x = m2[((size_t)(sg * 64 + sl) * N_DIM + i) * CM + lane];
    float s = x, sq = x * x;
#pragma unroll
    for (int off = 32; off; off >>= 1) {
      s += __shfl_xor(s, off);
      sq += __shfl_xor(sq, off);
    }
    float mu = s * (1.0f / CM);
    float var = sq * (1.0f / CM) - mu * mu;
    float rs = rsqrtf(var + 1e-5f);
    on[sl][lane] = (x - mu) * rs * gw + gb;
  }
  for (int idx = t; idx < 2048; idx += 256) {
    int k = idx >> 5, c = idx & 31;
    wl[0][k][c] = wa[idx];
    wl[1][k][c] = wb[idx];
  }
  __syncthreads();
  int s = t >> 2, c0 = (t & 3) * 8;
  float accA[8], accB[8];
#pragma unroll
  for (int j = 0; j < 8; ++j) { accA[j] = 0.0f; accB[j] = 0.0f; }
  for (int k = 0; k < 64; ++k) {
    float ov = on[s][k];
#pragma unroll
    for (int j = 0; j < 8; ++j) {
      accA[j] += ov * wl[0][k][c0 + j];
      accB[j] += ov * wl[1][k][c0 + j];
    }
  }
#pragma unroll
  for (int j = 0; j < 8; ++j) {
    tl[0][c0 + j][s] = accA[j];
    tl[1][c0 + j][s] = accB[j];
  }
  __syncthreads();
  int cc = t >> 3, s8 = (t & 7) * 8;
  size_t ob = ((size_t)i * 32 + cc) * 512 + (size_t)sg * 64 + s8;
  unsigned int p0 = 0, p1 = 0;
  p0 = __builtin_amdgcn_cvt_pk_fp8_f32(tl[0][cc][s8 + 0], tl[0][cc][s8 + 1], p0, false);
  p0 = __builtin_amdgcn_cvt_pk_fp8_f32(tl[0][cc][s8 + 2], tl[0][cc][s8 + 3], p0, true);
  p1 = __builtin_amdgcn_cvt_pk_fp8_f32(tl[0][cc][s8 + 4], tl[0][cc][s8 + 5], p1, false);
  p1 = __builtin_amdgcn_cvt_pk_fp8_f32(tl[0][cc][s8 + 6], tl[0][cc][s8 + 7], p1, true);
  uint2 pa = {p0, p1};
  *reinterpret_cast<uint2*>(at8 + ob) = pa;
  p0 = 0; p1 = 0;
  p0 = __builtin_amdgcn_cvt_pk_fp8_f32(tl[1][cc][s8 + 0], tl[1][cc][s8 + 1], p0, false);
  p0 = __builtin_amdgcn_cvt_pk_fp8_f32(tl[1][cc][s8 + 2], tl[1][cc][s8 + 3], p0, true);
  p1 = __builtin_amdgcn_cvt_pk_fp8_f32(tl[1][cc][s8 + 4], tl[1][cc][s8 + 5], p1, false);
  p1 = __builtin_amdgcn_cvt_pk_fp8_f32(tl[1][cc][s8 + 6], tl[1][cc][s8 + 7], p1, true);
  uint2 pb = {p0, p1};
  *reinterpret_cast<uint2*>(bt8 + ob) = pb;
}

// ---------------- wo_f: fragment-packed wo (bf16) for k_opm -----------------
__global__ __launch_bounds__(256) void k_wot(const float* __restrict__ wo,
                                             short* __restrict__ wo_f) {
  int tg = blockIdx.x * 256 + threadIdx.x;
  int frag = tg >> 6, lane = tg & 63;
  int eblk = frag >> 5, kc = frag & 31;
  int e = eblk * 16 + (lane & 15);
  int kbase = kc * 32 + (lane >> 4) * 8;
  short out[8];
#pragma unroll
  for (int j = 0; j < 8; ++j) out[j] = f2bs(wo[(size_t)(kbase + j) * CZ + e]);
  *reinterpret_cast<float4*>(&wo_f[(size_t)tg * 8]) =
      *reinterpret_cast<const float4*>(out);
}

// ---------------- OPM: fp8 MFMA 256x256, 16 waves, lean epilogue ------------
__global__ __launch_bounds__(1024, 4) void k_opm(const unsigned char* __restrict__ at8,
                                                 const unsigned char* __restrict__ bt8,
                                                 const short* __restrict__ wo_f,
                                                 const float* __restrict__ bo,
                                                 const float* __restrict__ z0,
                                                 float* __restrict__ z1) {
  // 2D XCD regions: each XCD owns 12 bm x 24 bn (bijective, 2304 = 8*288)
  int g = blockIdx.x;
  int xcd = g & 7, u = g >> 3;
  int bm = (xcd >> 1) * 12 + (u % 12);
  int bn = (xcd & 1) * 24 + (u / 12);
  __shared__ __align__(16) char lds8[66560];  // A: 2x16KB @0, B: 2x16KB @32768
  char* LA = lds8;
  char* LB = lds8 + 32768;
  int t = threadIdx.x, wave = t >> 6, lane = t & 63;
  int wm = wave >> 2, wn = wave & 3;
  int lg = lane >> 4, l15 = lane & 15;
  f32x4 acc[4][4];
#pragma unroll
  for (int a = 0; a < 4; ++a)
#pragma unroll
    for (int b = 0; b < 4; ++b) acc[a][b] = (f32x4){0.f, 0.f, 0.f, 0.f};
  const unsigned char* A = at8 + (size_t)bm * 131072;
  const unsigned char* B = bt8 + (size_t)bn * 131072;

  auto STAGE = [&](int buf, int kt) {
    int m = t >> 2, sl = t & 3;
    int so = kt * 64 + ((sl ^ ((m >> 1) & 3)) << 4);
    gl_lds16(A + (size_t)m * 512 + so, LA + buf * 16384 + t * 16);
    gl_lds16(B + (size_t)m * 512 + so, LB + buf * 16384 + t * 16);
  };

  STAGE(0, 0);
  __syncthreads();
  for (int kt = 0; kt < 8; ++kt) {
    int cur = kt & 1;
    if (kt < 7) STAGE(cur ^ 1, kt + 1);
#pragma unroll
    for (int ks = 0; ks < 2; ++ks) {
      int kk = ks * 32 + lg * 8;
      i64 bfr[4];
#pragma unroll
      for (int fn = 0; fn < 4; ++fn) {
        int n = wn * 64 + fn * 16 + l15;
        bfr[fn] = *reinterpret_cast<const i64*>(
            LB + cur * 16384 + n * 64 + (kk ^ (((n >> 1) & 3) << 4)));
      }
#pragma unroll
      for (int fm = 0; fm < 4; ++fm) {
        int m = wm * 64 + fm * 16 + l15;
        i64 af = *reinterpret_cast<const i64*>(
            LA + cur * 16384 + m * 64 + (kk ^ (((m >> 1) & 3) << 4)));
#pragma unroll
        for (int fn = 0; fn < 4; ++fn)
          acc[fm][fn] = __builtin_amdgcn_mfma_f32_16x16x32_fp8_fp8(
              af, bfr[fn], acc[fm][fn], 0, 0, 0);
      }
    }
    __syncthreads();
  }

  // --- epilogue: 2 rounds x 2 chunks (chunk = 64 m-rows = wm), 16 waves ---
  short* P2 = (short*)lds8;          // 2 x 16 x 1032 bf16 = 66048 B
  float* zbuf = (float*)lds8;        // 32 x 132 f32 = 16896 B (after P2 done)
  const float inv_s = 1.0f / 512.0f;
  int psel = wave >> 3;              // proj: which chunk this wave projects
  int eblk = wave & 7;               // proj: e block (16 e-cols)
#pragma unroll
  for (int rt = 0; rt < 2; ++rt) {
    // write P for chunks {2rt, 2rt+1}: waves with wm in {2rt, 2rt+1}
    if ((wm >> 1) == rt) {
      int sel = wm & 1;
#pragma unroll
      for (int fm = 0; fm < 4; ++fm)
#pragma unroll
        for (int fn = 0; fn < 4; ++fn)
#pragma unroll
          for (int r = 0; r < 4; ++r) {
            int m = wm * 64 + fm * 16 + lg * 4 + r;
            int n = wn * 64 + fn * 16 + l15;
            int prow = ((m >> 5) & 1) * 8 + (n >> 5);
            int cd = ((m & 31) << 5) | (n & 31);
            int pc = cd ^ (((cd >> 7) & 7) << 3);
            P2[sel * 16512 + prow * 1032 + pc] = f2bs(acc[fm][fn][r] * inv_s);
          }
    }
    __syncthreads();
    // projection: all 16 waves; wave -> (chunk psel, e block eblk)
    f32x4 pacc = (f32x4){0.f, 0.f, 0.f, 0.f};
    for (int c0 = 0; c0 < 1024; c0 += 32) {
      int col = c0 + lg * 8;
      int pc = col ^ (((col >> 7) & 7) << 3);
      bf16x8 pa = *reinterpret_cast<const bf16x8*>(P2 + psel * 16512 + l15 * 1032 + pc);
      bf16x8 pb = *reinterpret_cast<const bf16x8*>(
          wo_f + ((size_t)(eblk * 32 + (c0 >> 5)) * 64 + lane) * 8);
      pacc = __builtin_amdgcn_mfma_f32_16x16x32_bf16(pa, pb, pacc, 0, 0, 0);
    }
    __syncthreads();  // P2 reads done; zbuf overlays
#pragma unroll
    for (int r = 0; r < 4; ++r)
      zbuf[(psel * 16 + lg * 4 + r) * 132 + eblk * 16 + l15] = pacc[r];
    __syncthreads();
    // cooperative full-line z update: 32 pairs x 128 e, one float4/thread
    {
      int row = t >> 5, col4 = (t & 31) * 4;
      int p = rt * 32 + row;
      int gi = bm * 8 + (p >> 3), gj = bn * 8 + (p & 7);
      size_t addr = ((size_t)gi * N_DIM + gj) * CZ + col4;
      float4 zv = *reinterpret_cast<const float4*>(z0 + addr);
      float4 r4 = *reinterpret_cast<const float4*>(zbuf + row * 132 + col4);
      float4 b4 = *reinterpret_cast<const float4*>(bo + col4);
      float4 outv;
      outv.x = zv.x + r4.x + b4.x;
      outv.y = zv.y + r4.y + b4.y;
      outv.z = zv.z + r4.z + b4.z;
      outv.w = zv.w + r4.w + b4.w;
      *reinterpret_cast<float4*>(z1 + addr) = outv;
    }
    __syncthreads();  // zbuf/P2 region reused next round
  }
}

// ---------------------------------------------------------------------------
extern "C" void kernel_launch(void* const* d_in, const int* in_sizes, int n_in,
                              void* d_out, int out_size, void* d_ws, size_t ws_size,
                              hipStream_t stream) {
  const float* m0 = (const float*)d_in[0];
  const float* z0 = (const float*)d_in[1];
  const float* pwa_nm_w = (const float*)d_in[2];
  const float* pwa_nm_b = (const float*)d_in[3];
  const float* pwa_nz_w = (const float*)d_in[4];
  const float* pwa_nz_b = (const float*)d_in[5];
  const float* pwa_wm = (const float*)d_in[6];
  const float* pwa_wg = (const float*)d_in[7];
  const float* pwa_wz = (const float*)d_in[8];
  const float* pwa_wo = (const float*)d_in[9];
  const float* tr_nw = (const float*)d_in[10];
  const float* tr_nb = (const float*)d_in[11];
  const float* tr_w1 = (const float*)d_in[12];
  const float* tr_w2 = (const float*)d_in[13];
  const float* tr_w3 = (const float*)d_in[14];
  const float* opm_nw = (const float*)d_in[15];
  const float* opm_nb = (const float*)d_in[16];
  const float* opm_wa = (const float*)d_in[17];
  const float* opm_wb = (const float*)d_in[18];
  const float* opm_wo = (const float*)d_in[19];
  const float* opm_bo = (const float*)d_in[20];

  char* ws = (char*)d_ws;
  bf16* mn = (bf16*)(ws);                        // 25,165,824 B
  float* wbuf = (float*)(ws + 25165824);         //  4,718,592 B
  short* vT = (short*)(ws + 29884416);           // 100,663,296 B
  bf16* o = (bf16*)(ws + 130547712);             // 100,663,296 B
  // reuse dead vT region after k_ogemm:
  unsigned char* at8 = (unsigned char*)(ws + 29884416);  // 6,291,456 B
  unsigned char* bt8 = at8 + 6291456;                    // 6,291,456 B
  short* wo_f = (short*)(ws + 55050240);                 //   262,144 B

  float* m_out = (float*)d_out;
  float* z1 = m_out + (size_t)S_DIM * N_DIM * CM;
  // scratch in the z1 region of d_out (dead until k_opm overwrites all of z1)
  short* packW = (short*)z1;                     // 6 x 32 KB
  short* wm_f = packW;
  short* wg_f = packW + 16384;
  short* w1_f = packW + 32768;
  short* w2_f = packW + 49152;
  short* wpo_f = packW + 65536;
  short* w3_f = packW + 81920;
  short* w8 = (short*)((char*)z1 + 262144);      // 2,359,296 B (bf16 softmax W)

  k_wprep<<<48, 256, 0, stream>>>(pwa_wm, pwa_wg, tr_w1, tr_w2, pwa_wo, tr_w3, packW);
  k_ln_m<<<49152, 256, 0, stream>>>(m0, pwa_nm_w, pwa_nm_b, mn);
  k_zb<<<36864, 256, 0, stream>>>(z0, pwa_nz_w, pwa_nz_b, pwa_wz, wbuf);
  k_softmax<<<3072, 128, 0, stream>>>(wbuf);
  k_wsm8<<<576, 256, 0, stream>>>(wbuf, w8);
  k_vgemm<<<3072, 256, 0, stream>>>(mn, wm_f, vT);
  k_ogemm<<<dim3(192, 8), 256, 0, stream>>>(w8, vT, o);
  k_pwa_out<<<3072, 256, 0, stream>>>(mn, o, m0, wg_f, wpo_f, m_out);
  k_wot<<<64, 256, 0, stream>>>(opm_wo, wo_f);
  k_transition<<<3072, 256, 0, stream>>>(tr_nw, tr_nb, w1_f, w2_f, w3_f, m_out);
  k_opm_ab<<<3072, 256, 0, stream>>>(m_out, opm_nw, opm_nb, opm_wa, opm_wb, at8, bt8);
  k_opm<<<2304, 1024, 0, stream>>>(at8, bt8, wo_f, opm_bo, z0, z1);
}